// Round 1
// baseline (3450.709 us; speedup 1.0000x reference)
//
#include <hip/hip_runtime.h>

constexpr int NTYPES = 8;
constexpr int NREL   = 6;
constexpr int D      = 256;
constexpr int DIN    = 512;

// ---------- small prep kernels ----------
__global__ void k_count_types(const int* __restrict__ ntype, int* cnt, int N) {
  int i = blockIdx.x * blockDim.x + threadIdx.x;
  if (i < N) atomicAdd(&cnt[ntype[i]], 1);
}

__global__ void k_scan_types(const int* __restrict__ cnt, int* off, int* cursor) {
  if (threadIdx.x == 0) {
    int s = 0;
    for (int t = 0; t < NTYPES; ++t) { off[t] = s; cursor[t] = s; s += cnt[t]; }
  }
}

__global__ void k_scatter_perm(const int* __restrict__ ntype, int* cursor, int* perm, int N) {
  int i = blockIdx.x * blockDim.x + threadIdx.x;
  if (i < N) { int p = atomicAdd(&cursor[ntype[i]], 1); perm[p] = i; }
}

__global__ void k_degree(const int* __restrict__ dst, int* deg, int E) {
  int i = blockIdx.x * blockDim.x + threadIdx.x;
  if (i < E) atomicAdd(&deg[dst[i]], 1);
}

__global__ void k_invdeg(const int* __restrict__ deg, float* __restrict__ inv, int N) {
  int i = blockIdx.x * blockDim.x + threadIdx.x;
  if (i < N) inv[i] = 1.0f / fmaxf((float)deg[i], 1.0f);
}

// ---------- adaptation GEMM: h[i] = tanh(x_i @ W[t_i]^T + b[t_i]) ----------
// rows gathered through type-sorted perm so each block shares one type's W.
// BM=64, BN=64, BK=16, 256 threads, 4x4 micro-tile.
__global__ __launch_bounds__(256)
void k_adapt_gemm(const float* __restrict__ X,     // [N, DIN]
                  const float* __restrict__ W,     // [NTYPES, D, DIN]
                  const float* __restrict__ bias,  // [NTYPES, D]
                  const int* __restrict__ perm,
                  const int* __restrict__ cnt,
                  const int* __restrict__ off,
                  float* __restrict__ H, int N) {
  const int t  = blockIdx.z;
  const int m0 = blockIdx.x * 64;
  const int tcnt = cnt[t];
  if (m0 >= tcnt) return;
  const int n0  = blockIdx.y * 64;
  const int tid = threadIdx.x;

  __shared__ float As[16][65];
  __shared__ float Bs[16][65];

  const int lk = tid & 15;   // k within K-tile
  const int lm = tid >> 4;   // row base (0..15), step 16
  const int ty = tid >> 4, tx = tid & 15;

  int rows[4];
#pragma unroll
  for (int u = 0; u < 4; ++u) {
    int rl = m0 + lm + u * 16;
    rows[u] = (rl < tcnt) ? perm[off[t] + rl] : -1;
  }

  const float* Wt = W + (size_t)t * D * DIN;
  float acc[4][4] = {};

  for (int k0 = 0; k0 < DIN; k0 += 16) {
#pragma unroll
    for (int u = 0; u < 4; ++u) {
      int mloc = lm + u * 16;
      As[lk][mloc] = (rows[u] >= 0) ? X[(size_t)rows[u] * DIN + k0 + lk] : 0.0f;
      Bs[lk][mloc] = Wt[(size_t)(n0 + mloc) * DIN + k0 + lk];
    }
    __syncthreads();
#pragma unroll
    for (int k = 0; k < 16; ++k) {
      float a[4], b[4];
#pragma unroll
      for (int i = 0; i < 4; ++i) a[i] = As[k][ty * 4 + i];
#pragma unroll
      for (int j = 0; j < 4; ++j) b[j] = Bs[k][tx * 4 + j];
#pragma unroll
      for (int i = 0; i < 4; ++i)
#pragma unroll
        for (int j = 0; j < 4; ++j) acc[i][j] += a[i] * b[j];
    }
    __syncthreads();
  }

#pragma unroll
  for (int i = 0; i < 4; ++i) {
    int rl = m0 + ty * 4 + i;
    if (rl >= tcnt) continue;
    int node = perm[off[t] + rl];
#pragma unroll
    for (int j = 0; j < 4; ++j) {
      int n = n0 + tx * 4 + j;
      H[(size_t)node * D + n] = tanhf(acc[i][j] + bias[t * D + n]);
    }
  }
}

// ---------- plain GEMM: C[N,D] = A[N,D] @ B[D,D] (row-major) ----------
__global__ __launch_bounds__(256)
void k_gemm_nn(const float* __restrict__ A,
               const float* __restrict__ B,
               float* __restrict__ C, int N) {
  const int m0 = blockIdx.x * 64;
  const int n0 = blockIdx.y * 64;
  const int tid = threadIdx.x;
  __shared__ float As[16][65];
  __shared__ float Bs[16][65];
  const int ty = tid >> 4, tx = tid & 15;
  const int lkA = tid & 15, lmA = tid >> 4;
  const int lnB = tid & 63, lkB = tid >> 6;
  float acc[4][4] = {};

  for (int k0 = 0; k0 < D; k0 += 16) {
#pragma unroll
    for (int u = 0; u < 4; ++u) {
      int m = m0 + lmA + u * 16;
      As[lkA][lmA + u * 16] = (m < N) ? A[(size_t)m * D + k0 + lkA] : 0.0f;
      Bs[lkB + u * 4][lnB]  = B[(size_t)(k0 + lkB + u * 4) * D + n0 + lnB];
    }
    __syncthreads();
#pragma unroll
    for (int k = 0; k < 16; ++k) {
      float a[4], b[4];
#pragma unroll
      for (int i = 0; i < 4; ++i) a[i] = As[k][ty * 4 + i];
#pragma unroll
      for (int j = 0; j < 4; ++j) b[j] = Bs[k][tx * 4 + j];
#pragma unroll
      for (int i = 0; i < 4; ++i)
#pragma unroll
        for (int j = 0; j < 4; ++j) acc[i][j] += a[i] * b[j];
    }
    __syncthreads();
  }

#pragma unroll
  for (int i = 0; i < 4; ++i) {
    int m = m0 + ty * 4 + i;
    if (m >= N) continue;
#pragma unroll
    for (int j = 0; j < 4; ++j)
      C[(size_t)m * D + n0 + tx * 4 + j] = acc[i][j];
  }
}

// ---------- edge scatter: agg[dst] += hW[src] for edges of relation r ----------
// one wave per edge, 4 floats/lane, f32 global atomics
__global__ void k_scatter(const float* __restrict__ hW,
                          const int* __restrict__ src,
                          const int* __restrict__ dst,
                          const int* __restrict__ et,
                          float* __restrict__ agg, int E, int r) {
  int e = blockIdx.x * 4 + (threadIdx.x >> 6);
  if (e >= E) return;
  if (et[e] != r) return;
  int lane = threadIdx.x & 63;
  const float4 v = ((const float4*)(hW + (size_t)src[e] * D))[lane];
  float* a = agg + (size_t)dst[e] * D + lane * 4;
  atomicAdd(a + 0, v.x);
  atomicAdd(a + 1, v.y);
  atomicAdd(a + 2, v.z);
  atomicAdd(a + 3, v.w);
}

// ---------- self GEMM + combine: out = relu(A@B + agg*inv + bias) ----------
__global__ __launch_bounds__(256)
void k_self_combine(const float* __restrict__ A,
                    const float* __restrict__ B,
                    const float* __restrict__ agg,
                    const float* __restrict__ inv,
                    const float* __restrict__ bias,
                    float* __restrict__ Hout, int N) {
  const int m0 = blockIdx.x * 64;
  const int n0 = blockIdx.y * 64;
  const int tid = threadIdx.x;
  __shared__ float As[16][65];
  __shared__ float Bs[16][65];
  const int ty = tid >> 4, tx = tid & 15;
  const int lkA = tid & 15, lmA = tid >> 4;
  const int lnB = tid & 63, lkB = tid >> 6;
  float acc[4][4] = {};

  for (int k0 = 0; k0 < D; k0 += 16) {
#pragma unroll
    for (int u = 0; u < 4; ++u) {
      int m = m0 + lmA + u * 16;
      As[lkA][lmA + u * 16] = (m < N) ? A[(size_t)m * D + k0 + lkA] : 0.0f;
      Bs[lkB + u * 4][lnB]  = B[(size_t)(k0 + lkB + u * 4) * D + n0 + lnB];
    }
    __syncthreads();
#pragma unroll
    for (int k = 0; k < 16; ++k) {
      float a[4], b[4];
#pragma unroll
      for (int i = 0; i < 4; ++i) a[i] = As[k][ty * 4 + i];
#pragma unroll
      for (int j = 0; j < 4; ++j) b[j] = Bs[k][tx * 4 + j];
#pragma unroll
      for (int i = 0; i < 4; ++i)
#pragma unroll
        for (int j = 0; j < 4; ++j) acc[i][j] += a[i] * b[j];
    }
    __syncthreads();
  }

#pragma unroll
  for (int i = 0; i < 4; ++i) {
    int m = m0 + ty * 4 + i;
    if (m >= N) continue;
    float invm = inv[m];
#pragma unroll
    for (int j = 0; j < 4; ++j) {
      int n = n0 + tx * 4 + j;
      float v = acc[i][j] + agg[(size_t)m * D + n] * invm + bias[n];
      Hout[(size_t)m * D + n] = fmaxf(v, 0.0f);
    }
  }
}

extern "C" void kernel_launch(void* const* d_in, const int* in_sizes, int n_in,
                              void* d_out, int out_size, void* d_ws, size_t ws_size,
                              hipStream_t stream) {
  const float* X       = (const float*)d_in[0];
  const int*   ntype   = (const int*)d_in[1];
  const int*   eidx    = (const int*)d_in[2];
  const int*   etype   = (const int*)d_in[3];
  const float* adapt_W = (const float*)d_in[5];
  const float* adapt_b = (const float*)d_in[6];
  const float* W_rel   = (const float*)d_in[7];
  const float* W_self  = (const float*)d_in[8];
  const float* b_self  = (const float*)d_in[9];

  const int N = in_sizes[1];
  const int E = in_sizes[3];
  const int* src = eidx;
  const int* dst = eidx + E;

  char* ws = (char*)d_ws;
  size_t o = 0;
  auto alloc = [&](size_t bytes) { void* p = ws + o; o += (bytes + 255) & ~255ull; return p; };
  float* h0   = (float*)alloc((size_t)N * D * 4);
  float* h1   = (float*)alloc((size_t)N * D * 4);
  float* hW   = (float*)alloc((size_t)N * D * 4);
  float* agg  = (float*)alloc((size_t)N * D * 4);
  int*   deg  = (int*)alloc((size_t)N * 4);
  float* inv  = (float*)alloc((size_t)N * 4);
  int*   perm = (int*)alloc((size_t)N * 4);
  int*   cnt  = (int*)alloc(NTYPES * 4);
  int*   off  = (int*)alloc(NTYPES * 4);
  int*   cur  = (int*)alloc(NTYPES * 4);

  hipMemsetAsync(deg, 0, (size_t)N * 4, stream);
  hipMemsetAsync(cnt, 0, NTYPES * 4, stream);

  const int thr = 256;
  k_count_types<<<(N + thr - 1) / thr, thr, 0, stream>>>(ntype, cnt, N);
  k_scan_types<<<1, 64, 0, stream>>>(cnt, off, cur);
  k_scatter_perm<<<(N + thr - 1) / thr, thr, 0, stream>>>(ntype, cur, perm, N);
  k_degree<<<(E + thr - 1) / thr, thr, 0, stream>>>(dst, deg, E);
  k_invdeg<<<(N + thr - 1) / thr, thr, 0, stream>>>(deg, inv, N);

  dim3 gAdapt((N + 63) / 64, D / 64, NTYPES);
  k_adapt_gemm<<<gAdapt, 256, 0, stream>>>(X, adapt_W, adapt_b, perm, cnt, off, h0, N);

  const float* hcur = h0;
  for (int l = 0; l < 2; ++l) {
    float* hnext = (l == 0) ? h1 : (float*)d_out;
    hipMemsetAsync(agg, 0, (size_t)N * D * 4, stream);
    dim3 g((N + 63) / 64, D / 64);
    for (int r = 0; r < NREL; ++r) {
      const float* Wlr = W_rel + ((size_t)l * NREL + r) * D * D;
      k_gemm_nn<<<g, 256, 0, stream>>>(hcur, Wlr, hW, N);
      k_scatter<<<(E + 3) / 4, 256, 0, stream>>>(hW, src, dst, etype, agg, E, r);
    }
    k_self_combine<<<g, 256, 0, stream>>>(hcur, W_self + (size_t)l * D * D, agg, inv,
                                          b_self + (size_t)l * D, hnext, N);
    hcur = hnext;
  }
}

// Round 2
// 429.216 us; speedup vs baseline: 8.0396x; 8.0396x over previous
//
#include <hip/hip_runtime.h>

constexpr int NTYPES = 8;
constexpr int NREL   = 6;
constexpr int NSLOT  = 7;          // 6 relations + self
constexpr int D      = 256;
constexpr int DIN    = 512;
constexpr int LDH    = NSLOT * D;  // 1792

using short8 = __attribute__((ext_vector_type(8))) short;
using f32x4  = __attribute__((ext_vector_type(4))) float;

__device__ __forceinline__ ushort f2b(float f) {  // f32 -> bf16 RNE
  unsigned u = __float_as_uint(f);
  u += 0x7fffu + ((u >> 16) & 1u);
  return (ushort)(u >> 16);
}
__device__ __forceinline__ float b2f(unsigned bits16) {
  return __uint_as_float(bits16 << 16);
}

#define GLOAD_LDS16(g, l)                                              \
  __builtin_amdgcn_global_load_lds(                                    \
      (__attribute__((address_space(1))) void*)(g),                    \
      (__attribute__((address_space(3))) void*)(l), 16, 0, 0)

// ---------------- prep kernels ----------------
__global__ void k_cvt_bf16(const float* __restrict__ in, ushort* __restrict__ out, int n4) {
  int i = blockIdx.x * blockDim.x + threadIdx.x;
  if (i >= n4) return;
  float4 v = ((const float4*)in)[i];
  ushort4 o;
  o.x = f2b(v.x); o.y = f2b(v.y); o.z = f2b(v.z); o.w = f2b(v.w);
  ((ushort4*)out)[i] = o;
}

// Wcat[l][s][e][d] = (s<6 ? W_rel[l][s][d][e] : W_self[l][d][e]) as bf16
__global__ void k_pack_wcat(const float* __restrict__ Wrel, const float* __restrict__ Wself,
                            ushort* __restrict__ Wcat) {
  int l = blockIdx.z, s = blockIdx.y;
  int o = blockIdx.x * 256 + threadIdx.x;   // over D*D
  int e = o >> 8, d = o & 255;
  float v = (s < NREL) ? Wrel[(((size_t)l * NREL + s) * D + d) * D + e]
                       : Wself[((size_t)l * D + d) * D + e];
  Wcat[(((size_t)l * NSLOT + s) * D + e) * D + d] = f2b(v);
}

__global__ void k_count_types(const int* __restrict__ ntype, int* cnt, int N) {
  int i = blockIdx.x * blockDim.x + threadIdx.x;
  if (i < N) atomicAdd(&cnt[ntype[i]], 1);
}
__global__ void k_scan_types(const int* __restrict__ cnt, int* off, int* cursor) {
  if (threadIdx.x == 0) {
    int s = 0;
    for (int t = 0; t < NTYPES; ++t) { off[t] = s; cursor[t] = s; s += cnt[t]; }
  }
}
__global__ void k_scatter_perm(const int* __restrict__ ntype, int* cursor, int* perm, int N) {
  int i = blockIdx.x * blockDim.x + threadIdx.x;
  if (i < N) { int p = atomicAdd(&cursor[ntype[i]], 1); perm[p] = i; }
}
__global__ void k_degree(const int* __restrict__ dst, int* deg, int E) {
  int i = blockIdx.x * blockDim.x + threadIdx.x;
  if (i < E) atomicAdd(&deg[dst[i]], 1);
}
__global__ void k_invdeg(const int* __restrict__ deg, float* __restrict__ inv, int N) {
  int i = blockIdx.x * blockDim.x + threadIdx.x;
  if (i < N) inv[i] = 1.0f / fmaxf((float)deg[i], 1.0f);
}

// ---------------- CSR build (3-phase scan + counting sort) ----------------
__global__ void k_scan_block(const int* __restrict__ deg, int* __restrict__ rowptr,
                             int* __restrict__ bsum, int N) {
  __shared__ int s[256];
  int i = blockIdx.x * 256 + threadIdx.x;
  int v = (i < N) ? deg[i] : 0;
  s[threadIdx.x] = v;
  __syncthreads();
  for (int o = 1; o < 256; o <<= 1) {
    int t = (threadIdx.x >= o) ? s[threadIdx.x - o] : 0;
    __syncthreads();
    s[threadIdx.x] += t;
    __syncthreads();
  }
  if (i < N) rowptr[i] = s[threadIdx.x] - v;   // exclusive within block
  if (threadIdx.x == 255) bsum[blockIdx.x] = s[255];
}
__global__ void k_scan_bsum(int* bsum, int nb) {
  if (threadIdx.x == 0) {
    int s = 0;
    for (int b = 0; b < nb; ++b) { int t = bsum[b]; bsum[b] = s; s += t; }
  }
}
__global__ void k_scan_add(int* __restrict__ rowptr, int* __restrict__ cursor,
                           const int* __restrict__ bsum, int N, int E) {
  int i = blockIdx.x * 256 + threadIdx.x;
  if (i < N) { int r = rowptr[i] + bsum[blockIdx.x]; rowptr[i] = r; cursor[i] = r; }
  if (i == 0) rowptr[N] = E;
}
__global__ void k_sortedges(const int* __restrict__ src, const int* __restrict__ dst,
                            const int* __restrict__ et, int* cursor,
                            int* __restrict__ epack, int E) {
  int e = blockIdx.x * 256 + threadIdx.x;
  if (e < E) {
    int pos = atomicAdd(&cursor[dst[e]], 1);
    epack[pos] = (src[e] << 3) | et[e];
  }
}

// ---------------- MFMA GEMM ----------------
// C[m][n] = sum_k A[m][k] * B[n][k]   (B stored row-per-output-col, k-contiguous)
// 128x128 tile, 4 waves (2x2 of 64x64), BK=32, bf16 in / f32 acc / bf16 out.
// ADAPT: A-rows gathered via type-sorted perm, B = per-type W, epilogue tanh(+bias).
template <int KDIM, bool ADAPT>
__global__ __launch_bounds__(256, 2)
void k_mfma_gemm(const ushort* __restrict__ A, const ushort* __restrict__ B,
                 const float* __restrict__ bias,
                 const int* __restrict__ perm, const int* __restrict__ cnt,
                 const int* __restrict__ off,
                 ushort* __restrict__ Cout, int N, int ldC) {
  int mcnt = N;
  const int* permt = nullptr;
  const ushort* Bt = B;
  const float* biast = bias;
  if (ADAPT) {
    int t = blockIdx.z;
    mcnt = cnt[t];
    permt = perm + off[t];
    Bt = B + (size_t)t * D * KDIM;
    biast = bias + t * D;
  }
  const int m0 = blockIdx.x * 128;
  if (m0 >= mcnt) return;
  const int n0 = blockIdx.y * 128;

  __shared__ ushort As[128 * 32];
  __shared__ ushort Bs[128 * 32];

  const int tid  = threadIdx.x;
  const int lane = tid & 63;
  const int w    = tid >> 6;
  const int wr   = (w >> 1) * 64;
  const int wc   = (w & 1) * 64;

  // staging: 8 x 1KB calls per matrix; wave w does calls {w, w+4}.
  // call c covers LDS rows [16c,16c+16); lane -> row 16c+(lane>>2), slot lane&3.
  // XOR swizzle: content slot' = slot ^ ((row>>1)&3), applied to GLOBAL source
  // (LDS dest stays linear — global_load_lds requirement), undone at ds_read.
  const int sr0 = w * 16 + (lane >> 2);
  const int sr1 = (w + 4) * 16 + (lane >> 2);
  const int sl0 = (lane & 3) ^ ((sr0 >> 1) & 3);
  const int sl1 = (lane & 3) ^ ((sr1 >> 1) & 3);

  int ga0, ga1;
  if (ADAPT) {
    ga0 = permt[min(m0 + sr0, mcnt - 1)];
    ga1 = permt[min(m0 + sr1, mcnt - 1)];
  } else {
    ga0 = min(m0 + sr0, N - 1);
    ga1 = min(m0 + sr1, N - 1);
  }
  const ushort* gA0 = A + (size_t)ga0 * KDIM + sl0 * 8;
  const ushort* gA1 = A + (size_t)ga1 * KDIM + sl1 * 8;
  const ushort* gB0 = Bt + (size_t)(n0 + sr0) * KDIM + sl0 * 8;
  const ushort* gB1 = Bt + (size_t)(n0 + sr1) * KDIM + sl1 * 8;

  ushort* lA0 = As + w * 512;          // 512 shorts = 1KB per call
  ushort* lA1 = As + (w + 4) * 512;
  ushort* lB0 = Bs + w * 512;
  ushort* lB1 = Bs + (w + 4) * 512;

  f32x4 acc[4][4] = {};

  const int r15 = lane & 15;
  const int g   = lane >> 4;
  const int gsw = g ^ ((r15 >> 1) & 3);  // swizzled k-slot for frag reads

  for (int k0 = 0; k0 < KDIM; k0 += 32) {
    GLOAD_LDS16(gA0 + k0, lA0);
    GLOAD_LDS16(gA1 + k0, lA1);
    GLOAD_LDS16(gB0 + k0, lB0);
    GLOAD_LDS16(gB1 + k0, lB1);
    __syncthreads();  // drains vmcnt (global_load_lds) for all waves

    short8 af[4], bf[4];
#pragma unroll
    for (int i = 0; i < 4; ++i) {
      int r = wr + i * 16 + r15;
      af[i] = *(const short8*)(As + r * 32 + gsw * 8);
      int c = wc + i * 16 + r15;
      bf[i] = *(const short8*)(Bs + c * 32 + gsw * 8);
    }
#pragma unroll
    for (int i = 0; i < 4; ++i)
#pragma unroll
      for (int j = 0; j < 4; ++j)
        acc[i][j] = __builtin_amdgcn_mfma_f32_16x16x32_bf16(af[i], bf[j], acc[i][j], 0, 0, 0);
    __syncthreads();  // all reads done before next stage overwrites
  }

  // C/D layout (m89-verified): col = lane&15, row = (lane>>4)*4 + reg
  if (ADAPT) {
#pragma unroll
    for (int i = 0; i < 4; ++i) {
#pragma unroll
      for (int q = 0; q < 4; ++q) {
        int rl = m0 + wr + i * 16 + (lane >> 4) * 4 + q;
        if (rl < mcnt) {
          int node = permt[rl];
#pragma unroll
          for (int j = 0; j < 4; ++j) {
            int n = n0 + wc + j * 16 + (lane & 15);
            Cout[(size_t)node * ldC + n] = f2b(tanhf(acc[i][j][q] + biast[n]));
          }
        }
      }
    }
  } else {
#pragma unroll
    for (int i = 0; i < 4; ++i) {
#pragma unroll
      for (int q = 0; q < 4; ++q) {
        int m = m0 + wr + i * 16 + (lane >> 4) * 4 + q;
        if (m < N) {
#pragma unroll
          for (int j = 0; j < 4; ++j) {
            int n = n0 + wc + j * 16 + (lane & 15);
            Cout[(size_t)m * ldC + n] = f2b(acc[i][j][q]);
          }
        }
      }
    }
  }
}

// ---------------- CSR gather-combine ----------------
// out[v] = relu( (sum_{e in in(v)} Hall[src_e][rel_e*256 + :]) * inv[v]
//                + Hall[v][6*256 + :] + bias )
// one wave per node, lane owns 4 channels.
template <bool LAST>
__global__ void k_combine(const ushort* __restrict__ Hall, const int* __restrict__ rowptr,
                          const int* __restrict__ epack, const float* __restrict__ invd,
                          const float* __restrict__ bias, void* __restrict__ outp, int N) {
  int v = blockIdx.x * 4 + (threadIdx.x >> 6);
  if (v >= N) return;
  int lane = threadIdx.x & 63;
  int e0 = rowptr[v], e1 = rowptr[v + 1];
  float a0 = 0.f, a1 = 0.f, a2 = 0.f, a3 = 0.f;
  for (int e = e0; e < e1; ++e) {
    int p = epack[e];
    const uint2 u = *(const uint2*)(Hall + (size_t)(p >> 3) * LDH + (p & 7) * D + lane * 4);
    a0 += b2f(u.x & 0xffffu);
    a1 += __uint_as_float(u.x & 0xffff0000u);
    a2 += b2f(u.y & 0xffffu);
    a3 += __uint_as_float(u.y & 0xffff0000u);
  }
  const uint2 s = *(const uint2*)(Hall + (size_t)v * LDH + NREL * D + lane * 4);
  float iv = invd[v];
  const float4 b4 = *(const float4*)(bias + lane * 4);
  float o0 = fmaxf(fmaf(a0, iv, b2f(s.x & 0xffffu)) + b4.x, 0.f);
  float o1 = fmaxf(fmaf(a1, iv, __uint_as_float(s.x & 0xffff0000u)) + b4.y, 0.f);
  float o2 = fmaxf(fmaf(a2, iv, b2f(s.y & 0xffffu)) + b4.z, 0.f);
  float o3 = fmaxf(fmaf(a3, iv, __uint_as_float(s.y & 0xffff0000u)) + b4.w, 0.f);
  if (LAST) {
    float4 o; o.x = o0; o.y = o1; o.z = o2; o.w = o3;
    ((float4*)outp)[(size_t)v * 64 + lane] = o;
  } else {
    ushort4 o; o.x = f2b(o0); o.y = f2b(o1); o.z = f2b(o2); o.w = f2b(o3);
    ((ushort4*)outp)[(size_t)v * 64 + lane] = o;
  }
}

extern "C" void kernel_launch(void* const* d_in, const int* in_sizes, int n_in,
                              void* d_out, int out_size, void* d_ws, size_t ws_size,
                              hipStream_t stream) {
  const float* X       = (const float*)d_in[0];
  const int*   ntype   = (const int*)d_in[1];
  const int*   eidx    = (const int*)d_in[2];
  const int*   etype   = (const int*)d_in[3];
  const float* adapt_W = (const float*)d_in[5];
  const float* adapt_b = (const float*)d_in[6];
  const float* W_rel   = (const float*)d_in[7];
  const float* W_self  = (const float*)d_in[8];
  const float* b_self  = (const float*)d_in[9];

  const int N = in_sizes[1];
  const int E = in_sizes[3];
  const int* src = eidx;
  const int* dst = eidx + E;

  char* ws = (char*)d_ws;
  size_t o = 0;
  auto alloc = [&](size_t bytes) { void* p = ws + o; o += (bytes + 255) & ~255ull; return p; };

  ushort* Hall  = (ushort*)alloc((size_t)N * LDH * 2);  // 71.7 MB; also aliases Xb
  ushort* Xb    = Hall;                                  // Xb (20.5 MB) dead before Hall written
  ushort* h     = (ushort*)alloc((size_t)N * D * 2);
  ushort* Wab   = (ushort*)alloc((size_t)NTYPES * D * DIN * 2);
  ushort* Wcat  = (ushort*)alloc((size_t)2 * NSLOT * D * D * 2);
  int*   deg    = (int*)alloc((size_t)N * 4);
  float* inv    = (float*)alloc((size_t)N * 4);
  int*   perm   = (int*)alloc((size_t)N * 4);
  int*   rowptr = (int*)alloc((size_t)(N + 1) * 4);
  int*   cursor = (int*)alloc((size_t)N * 4);
  int*   epack  = (int*)alloc((size_t)E * 4);
  int*   bsum   = (int*)alloc(1024 * 4);
  int*   cnt    = (int*)alloc(NTYPES * 4);
  int*   offt   = (int*)alloc(NTYPES * 4);
  int*   curt   = (int*)alloc(NTYPES * 4);

  hipMemsetAsync(deg, 0, (size_t)N * 4, stream);
  hipMemsetAsync(cnt, 0, NTYPES * 4, stream);

  const int thr = 256;
  const int nbN = (N + thr - 1) / thr;
  const int nbE = (E + thr - 1) / thr;

  // bf16 conversions / weight packing
  k_cvt_bf16<<<(N * DIN / 4 + thr - 1) / thr, thr, 0, stream>>>(X, Xb, N * DIN / 4);
  k_cvt_bf16<<<(NTYPES * D * DIN / 4 + thr - 1) / thr, thr, 0, stream>>>(adapt_W, Wab,
                                                                          NTYPES * D * DIN / 4);
  dim3 gW(D * D / 256, NSLOT, 2);
  k_pack_wcat<<<gW, 256, 0, stream>>>(W_rel, W_self, Wcat);

  // type sort + degrees
  k_count_types<<<nbN, thr, 0, stream>>>(ntype, cnt, N);
  k_scan_types<<<1, 64, 0, stream>>>(cnt, offt, curt);
  k_scatter_perm<<<nbN, thr, 0, stream>>>(ntype, curt, perm, N);
  k_degree<<<nbE, thr, 0, stream>>>(dst, deg, E);
  k_invdeg<<<nbN, thr, 0, stream>>>(deg, inv, N);

  // CSR by dst
  k_scan_block<<<nbN, 256, 0, stream>>>(deg, rowptr, bsum, N);
  k_scan_bsum<<<1, 64, 0, stream>>>(bsum, nbN);
  k_scan_add<<<nbN, 256, 0, stream>>>(rowptr, cursor, bsum, N, E);
  k_sortedges<<<nbE, 256, 0, stream>>>(src, dst, etype, cursor, epack, E);

  // adaptation: h = tanh(X @ W_t^T + b_t), bf16 out
  dim3 gA((N + 127) / 128, D / 128, NTYPES);
  k_mfma_gemm<DIN, true><<<gA, 256, 0, stream>>>(Xb, Wab, adapt_b, perm, cnt, offt, h, N, D);

  // two relational layers
  dim3 gL((N + 127) / 128, LDH / 128, 1);
  for (int l = 0; l < 2; ++l) {
    const ushort* Wl = Wcat + (size_t)l * NSLOT * D * D;
    k_mfma_gemm<D, false><<<gL, 256, 0, stream>>>(h, Wl, nullptr, nullptr, nullptr, nullptr,
                                                  Hall, N, LDH);
    if (l == 0)
      k_combine<false><<<(N + 3) / 4, 256, 0, stream>>>(Hall, rowptr, epack, inv,
                                                        b_self + (size_t)l * D, h, N);
    else
      k_combine<true><<<(N + 3) / 4, 256, 0, stream>>>(Hall, rowptr, epack, inv,
                                                       b_self + (size_t)l * D, d_out, N);
  }
}

// Round 3
// 297.492 us; speedup vs baseline: 11.5993x; 1.4428x over previous
//
#include <hip/hip_runtime.h>

constexpr int NTYPES = 8;
constexpr int NREL   = 6;
constexpr int NSLOT  = 7;          // 6 relations + self
constexpr int D      = 256;
constexpr int DIN    = 512;
constexpr int LDH    = NSLOT * D;  // 1792

using short8 = __attribute__((ext_vector_type(8))) short;
using f32x4  = __attribute__((ext_vector_type(4))) float;

__device__ __forceinline__ ushort f2b(float f) {  // f32 -> bf16 RNE
  unsigned u = __float_as_uint(f);
  u += 0x7fffu + ((u >> 16) & 1u);
  return (ushort)(u >> 16);
}
__device__ __forceinline__ float b2f(unsigned bits16) {
  return __uint_as_float(bits16 << 16);
}

#define GLOAD_LDS16(g, l)                                              \
  __builtin_amdgcn_global_load_lds(                                    \
      (__attribute__((address_space(1))) void*)(g),                    \
      (__attribute__((address_space(3))) void*)(l), 16, 0, 0)

// ---------------- prep kernels ----------------
__global__ void k_cvt_bf16(const float* __restrict__ in, ushort* __restrict__ out, int n4) {
  int i = blockIdx.x * blockDim.x + threadIdx.x;
  if (i >= n4) return;
  float4 v = ((const float4*)in)[i];
  ushort4 o;
  o.x = f2b(v.x); o.y = f2b(v.y); o.z = f2b(v.z); o.w = f2b(v.w);
  ((ushort4*)out)[i] = o;
}

// Wcat[l][s][e][d] = (s<6 ? W_rel[l][s][d][e] : W_self[l][d][e]) as bf16
__global__ void k_pack_wcat(const float* __restrict__ Wrel, const float* __restrict__ Wself,
                            ushort* __restrict__ Wcat) {
  int l = blockIdx.z, s = blockIdx.y;
  int o = blockIdx.x * 256 + threadIdx.x;   // over D*D
  int e = o >> 8, d = o & 255;
  float v = (s < NREL) ? Wrel[(((size_t)l * NREL + s) * D + d) * D + e]
                       : Wself[((size_t)l * D + d) * D + e];
  Wcat[(((size_t)l * NSLOT + s) * D + e) * D + d] = f2b(v);
}

// ---- contention-free counting sort by node type (ballot-based, 3 phases) ----
__global__ void k_type_blockcnt(const int* __restrict__ ntype, int* __restrict__ blockcnt,
                                int N) {
  __shared__ int cnt[NTYPES];
  int i = blockIdx.x * 256 + threadIdx.x;
  if (threadIdx.x < NTYPES) cnt[threadIdx.x] = 0;
  __syncthreads();
  int t = (i < N) ? ntype[i] : -1;
#pragma unroll
  for (int ty = 0; ty < NTYPES; ++ty) {
    unsigned long long m = __ballot(t == ty);
    if ((threadIdx.x & 63) == 0 && m) atomicAdd(&cnt[ty], __popcll(m));
  }
  __syncthreads();
  if (threadIdx.x < NTYPES) blockcnt[blockIdx.x * NTYPES + threadIdx.x] = cnt[threadIdx.x];
}

__global__ void k_type_scan(const int* __restrict__ blockcnt, int* __restrict__ boffset,
                            int* __restrict__ cnt, int* __restrict__ offt, int nb) {
  __shared__ int tot[NTYPES];
  __shared__ int base[NTYPES];
  int t = threadIdx.x;
  if (t < NTYPES) {
    int s = 0;
    for (int b = 0; b < nb; ++b) {
      boffset[b * NTYPES + t] = s;
      s += blockcnt[b * NTYPES + t];
    }
    tot[t] = s;
    cnt[t] = s;
  }
  __syncthreads();
  if (t == 0) {
    int s = 0;
    for (int ty = 0; ty < NTYPES; ++ty) { base[ty] = s; offt[ty] = s; s += tot[ty]; }
  }
  __syncthreads();
  if (t < NTYPES)
    for (int b = 0; b < nb; ++b) boffset[b * NTYPES + t] += base[t];
}

__global__ void k_type_scatter(const int* __restrict__ ntype, const int* __restrict__ boffset,
                               int* __restrict__ perm, int N) {
  __shared__ int cur[NTYPES];
  int i = blockIdx.x * 256 + threadIdx.x;
  if (threadIdx.x < NTYPES) cur[threadIdx.x] = boffset[blockIdx.x * NTYPES + threadIdx.x];
  __syncthreads();
  int t = (i < N) ? ntype[i] : -1;
  int lane = threadIdx.x & 63;
#pragma unroll
  for (int ty = 0; ty < NTYPES; ++ty) {
    unsigned long long m = __ballot(t == ty);
    if (m) {
      int wbase = 0;
      if (lane == 0) wbase = atomicAdd(&cur[ty], __popcll(m));
      wbase = __shfl(wbase, 0);
      if (t == ty) {
        int rank = __popcll(m & ((1ull << lane) - 1ull));
        perm[wbase + rank] = i;
      }
    }
  }
}

__global__ void k_degree(const int* __restrict__ dst, int* deg, int E) {
  int i = blockIdx.x * blockDim.x + threadIdx.x;
  if (i < E) atomicAdd(&deg[dst[i]], 1);
}
__global__ void k_invdeg(const int* __restrict__ deg, float* __restrict__ inv, int N) {
  int i = blockIdx.x * blockDim.x + threadIdx.x;
  if (i < N) inv[i] = 1.0f / fmaxf((float)deg[i], 1.0f);
}

// ---------------- CSR build (3-phase scan + counting sort) ----------------
__global__ void k_scan_block(const int* __restrict__ deg, int* __restrict__ rowptr,
                             int* __restrict__ bsum, int N) {
  __shared__ int s[256];
  int i = blockIdx.x * 256 + threadIdx.x;
  int v = (i < N) ? deg[i] : 0;
  s[threadIdx.x] = v;
  __syncthreads();
  for (int o = 1; o < 256; o <<= 1) {
    int t = (threadIdx.x >= o) ? s[threadIdx.x - o] : 0;
    __syncthreads();
    s[threadIdx.x] += t;
    __syncthreads();
  }
  if (i < N) rowptr[i] = s[threadIdx.x] - v;   // exclusive within block
  if (threadIdx.x == 255) bsum[blockIdx.x] = s[255];
}
__global__ void k_scan_bsum(int* bsum, int nb) {
  if (threadIdx.x == 0) {
    int s = 0;
    for (int b = 0; b < nb; ++b) { int t = bsum[b]; bsum[b] = s; s += t; }
  }
}
__global__ void k_scan_add(int* __restrict__ rowptr, int* __restrict__ cursor,
                           const int* __restrict__ bsum, int N, int E) {
  int i = blockIdx.x * 256 + threadIdx.x;
  if (i < N) { int r = rowptr[i] + bsum[blockIdx.x]; rowptr[i] = r; cursor[i] = r; }
  if (i == 0) rowptr[N] = E;
}
__global__ void k_sortedges(const int* __restrict__ src, const int* __restrict__ dst,
                            const int* __restrict__ et, int* cursor,
                            int* __restrict__ epack, int E) {
  int e = blockIdx.x * 256 + threadIdx.x;
  if (e < E) {
    int pos = atomicAdd(&cursor[dst[e]], 1);
    epack[pos] = (src[e] << 3) | et[e];
  }
}

// ---------------- MFMA GEMM ----------------
// C[m][n] = sum_k A[m][k] * B[n][k]   (B stored row-per-output-col, k-contiguous)
// 128x128 tile, 4 waves (2x2 of 64x64), BK=32, bf16 in / f32 acc / bf16 out.
// ADAPT: A-rows gathered via type-sorted perm, B = per-type W, epilogue tanh(+bias).
template <int KDIM, bool ADAPT>
__global__ __launch_bounds__(256, 2)
void k_mfma_gemm(const ushort* __restrict__ A, const ushort* __restrict__ B,
                 const float* __restrict__ bias,
                 const int* __restrict__ perm, const int* __restrict__ cnt,
                 const int* __restrict__ off,
                 ushort* __restrict__ Cout, int N, int ldC) {
  int mcnt = N;
  const int* permt = nullptr;
  const ushort* Bt = B;
  const float* biast = bias;
  if (ADAPT) {
    int t = blockIdx.z;
    mcnt = cnt[t];
    permt = perm + off[t];
    Bt = B + (size_t)t * D * KDIM;
    biast = bias + t * D;
  }
  const int m0 = blockIdx.x * 128;
  if (m0 >= mcnt) return;
  const int n0 = blockIdx.y * 128;

  __shared__ ushort As[128 * 32];
  __shared__ ushort Bs[128 * 32];

  const int tid  = threadIdx.x;
  const int lane = tid & 63;
  const int w    = tid >> 6;
  const int wr   = (w >> 1) * 64;
  const int wc   = (w & 1) * 64;

  // staging: 8 x 1KB calls per matrix; wave w does calls {w, w+4}.
  // call c covers LDS rows [16c,16c+16); lane -> row 16c+(lane>>2), slot lane&3.
  // XOR swizzle: content slot' = slot ^ ((row>>1)&3), applied to GLOBAL source
  // (LDS dest stays linear — global_load_lds requirement), undone at ds_read.
  const int sr0 = w * 16 + (lane >> 2);
  const int sr1 = (w + 4) * 16 + (lane >> 2);
  const int sl0 = (lane & 3) ^ ((sr0 >> 1) & 3);
  const int sl1 = (lane & 3) ^ ((sr1 >> 1) & 3);

  int ga0, ga1;
  if (ADAPT) {
    ga0 = permt[min(m0 + sr0, mcnt - 1)];
    ga1 = permt[min(m0 + sr1, mcnt - 1)];
  } else {
    ga0 = min(m0 + sr0, N - 1);
    ga1 = min(m0 + sr1, N - 1);
  }
  const ushort* gA0 = A + (size_t)ga0 * KDIM + sl0 * 8;
  const ushort* gA1 = A + (size_t)ga1 * KDIM + sl1 * 8;
  const ushort* gB0 = Bt + (size_t)(n0 + sr0) * KDIM + sl0 * 8;
  const ushort* gB1 = Bt + (size_t)(n0 + sr1) * KDIM + sl1 * 8;

  ushort* lA0 = As + w * 512;          // 512 shorts = 1KB per call
  ushort* lA1 = As + (w + 4) * 512;
  ushort* lB0 = Bs + w * 512;
  ushort* lB1 = Bs + (w + 4) * 512;

  f32x4 acc[4][4] = {};

  const int r15 = lane & 15;
  const int g   = lane >> 4;
  const int gsw = g ^ ((r15 >> 1) & 3);  // swizzled k-slot for frag reads

  for (int k0 = 0; k0 < KDIM; k0 += 32) {
    GLOAD_LDS16(gA0 + k0, lA0);
    GLOAD_LDS16(gA1 + k0, lA1);
    GLOAD_LDS16(gB0 + k0, lB0);
    GLOAD_LDS16(gB1 + k0, lB1);
    __syncthreads();  // drains vmcnt (global_load_lds) for all waves

    short8 af[4], bf[4];
#pragma unroll
    for (int i = 0; i < 4; ++i) {
      int r = wr + i * 16 + r15;
      af[i] = *(const short8*)(As + r * 32 + gsw * 8);
      int c = wc + i * 16 + r15;
      bf[i] = *(const short8*)(Bs + c * 32 + gsw * 8);
    }
#pragma unroll
    for (int i = 0; i < 4; ++i)
#pragma unroll
      for (int j = 0; j < 4; ++j)
        acc[i][j] = __builtin_amdgcn_mfma_f32_16x16x32_bf16(af[i], bf[j], acc[i][j], 0, 0, 0);
    __syncthreads();  // all reads done before next stage overwrites
  }

  // C/D layout (m89-verified): col = lane&15, row = (lane>>4)*4 + reg
  if (ADAPT) {
#pragma unroll
    for (int i = 0; i < 4; ++i) {
#pragma unroll
      for (int q = 0; q < 4; ++q) {
        int rl = m0 + wr + i * 16 + (lane >> 4) * 4 + q;
        if (rl < mcnt) {
          int node = permt[rl];
#pragma unroll
          for (int j = 0; j < 4; ++j) {
            int n = n0 + wc + j * 16 + (lane & 15);
            Cout[(size_t)node * ldC + n] = f2b(tanhf(acc[i][j][q] + biast[n]));
          }
        }
      }
    }
  } else {
#pragma unroll
    for (int i = 0; i < 4; ++i) {
#pragma unroll
      for (int q = 0; q < 4; ++q) {
        int m = m0 + wr + i * 16 + (lane >> 4) * 4 + q;
        if (m < N) {
#pragma unroll
          for (int j = 0; j < 4; ++j) {
            int n = n0 + wc + j * 16 + (lane & 15);
            Cout[(size_t)m * ldC + n] = f2b(acc[i][j][q]);
          }
        }
      }
    }
  }
}

// ---------------- CSR gather-combine ----------------
// out[v] = relu( (sum_{e in in(v)} Hall[src_e][rel_e*256 + :]) * inv[v]
//                + Hall[v][6*256 + :] + bias )
// one wave per node, lane owns 4 channels.
template <bool LAST>
__global__ void k_combine(const ushort* __restrict__ Hall, const int* __restrict__ rowptr,
                          const int* __restrict__ epack, const float* __restrict__ invd,
                          const float* __restrict__ bias, void* __restrict__ outp, int N) {
  int v = blockIdx.x * 4 + (threadIdx.x >> 6);
  if (v >= N) return;
  int lane = threadIdx.x & 63;
  int e0 = rowptr[v], e1 = rowptr[v + 1];
  float a0 = 0.f, a1 = 0.f, a2 = 0.f, a3 = 0.f;
  for (int e = e0; e < e1; ++e) {
    int p = epack[e];
    const uint2 u = *(const uint2*)(Hall + (size_t)(p >> 3) * LDH + (p & 7) * D + lane * 4);
    a0 += b2f(u.x & 0xffffu);
    a1 += __uint_as_float(u.x & 0xffff0000u);
    a2 += b2f(u.y & 0xffffu);
    a3 += __uint_as_float(u.y & 0xffff0000u);
  }
  const uint2 s = *(const uint2*)(Hall + (size_t)v * LDH + NREL * D + lane * 4);
  float iv = invd[v];
  const float4 b4 = *(const float4*)(bias + lane * 4);
  float o0 = fmaxf(fmaf(a0, iv, b2f(s.x & 0xffffu)) + b4.x, 0.f);
  float o1 = fmaxf(fmaf(a1, iv, __uint_as_float(s.x & 0xffff0000u)) + b4.y, 0.f);
  float o2 = fmaxf(fmaf(a2, iv, b2f(s.y & 0xffffu)) + b4.z, 0.f);
  float o3 = fmaxf(fmaf(a3, iv, __uint_as_float(s.y & 0xffff0000u)) + b4.w, 0.f);
  if (LAST) {
    float4 o; o.x = o0; o.y = o1; o.z = o2; o.w = o3;
    ((float4*)outp)[(size_t)v * 64 + lane] = o;
  } else {
    ushort4 o; o.x = f2b(o0); o.y = f2b(o1); o.z = f2b(o2); o.w = f2b(o3);
    ((ushort4*)outp)[(size_t)v * 64 + lane] = o;
  }
}

extern "C" void kernel_launch(void* const* d_in, const int* in_sizes, int n_in,
                              void* d_out, int out_size, void* d_ws, size_t ws_size,
                              hipStream_t stream) {
  const float* X       = (const float*)d_in[0];
  const int*   ntype   = (const int*)d_in[1];
  const int*   eidx    = (const int*)d_in[2];
  const int*   etype   = (const int*)d_in[3];
  const float* adapt_W = (const float*)d_in[5];
  const float* adapt_b = (const float*)d_in[6];
  const float* W_rel   = (const float*)d_in[7];
  const float* W_self  = (const float*)d_in[8];
  const float* b_self  = (const float*)d_in[9];

  const int N = in_sizes[1];
  const int E = in_sizes[3];
  const int* src = eidx;
  const int* dst = eidx + E;

  char* ws = (char*)d_ws;
  size_t o = 0;
  auto alloc = [&](size_t bytes) { void* p = ws + o; o += (bytes + 255) & ~255ull; return p; };

  ushort* Hall  = (ushort*)alloc((size_t)N * LDH * 2);  // 71.7 MB; also aliases Xb
  ushort* Xb    = Hall;                                  // Xb (20.5 MB) dead before Hall written
  ushort* h     = (ushort*)alloc((size_t)N * D * 2);
  ushort* Wab   = (ushort*)alloc((size_t)NTYPES * D * DIN * 2);
  ushort* Wcat  = (ushort*)alloc((size_t)2 * NSLOT * D * D * 2);
  int*   deg    = (int*)alloc((size_t)N * 4);
  float* inv    = (float*)alloc((size_t)N * 4);
  int*   perm   = (int*)alloc((size_t)N * 4);
  int*   rowptr = (int*)alloc((size_t)(N + 1) * 4);
  int*   cursor = (int*)alloc((size_t)N * 4);
  int*   epack  = (int*)alloc((size_t)E * 4);
  int*   bsum   = (int*)alloc(1024 * 4);
  int*   blockcnt = (int*)alloc((size_t)1024 * NTYPES * 4);
  int*   boffset  = (int*)alloc((size_t)1024 * NTYPES * 4);
  int*   cnt    = (int*)alloc(NTYPES * 4);
  int*   offt   = (int*)alloc(NTYPES * 4);

  hipMemsetAsync(deg, 0, (size_t)N * 4, stream);

  const int thr = 256;
  const int nbN = (N + thr - 1) / thr;
  const int nbE = (E + thr - 1) / thr;

  // bf16 conversions / weight packing
  k_cvt_bf16<<<(N * DIN / 4 + thr - 1) / thr, thr, 0, stream>>>(X, Xb, N * DIN / 4);
  k_cvt_bf16<<<(NTYPES * D * DIN / 4 + thr - 1) / thr, thr, 0, stream>>>(adapt_W, Wab,
                                                                          NTYPES * D * DIN / 4);
  dim3 gW(D * D / 256, NSLOT, 2);
  k_pack_wcat<<<gW, 256, 0, stream>>>(W_rel, W_self, Wcat);

  // type sort (ballot-based, contention-free) + degrees
  k_type_blockcnt<<<nbN, thr, 0, stream>>>(ntype, blockcnt, N);
  k_type_scan<<<1, 64, 0, stream>>>(blockcnt, boffset, cnt, offt, nbN);
  k_type_scatter<<<nbN, thr, 0, stream>>>(ntype, boffset, perm, N);
  k_degree<<<nbE, thr, 0, stream>>>(dst, deg, E);
  k_invdeg<<<nbN, thr, 0, stream>>>(deg, inv, N);

  // CSR by dst
  k_scan_block<<<nbN, 256, 0, stream>>>(deg, rowptr, bsum, N);
  k_scan_bsum<<<1, 64, 0, stream>>>(bsum, nbN);
  k_scan_add<<<nbN, 256, 0, stream>>>(rowptr, cursor, bsum, N, E);
  k_sortedges<<<nbE, 256, 0, stream>>>(src, dst, etype, cursor, epack, E);

  // adaptation: h = tanh(X @ W_t^T + b_t), bf16 out
  dim3 gA((N + 127) / 128, D / 128, NTYPES);
  k_mfma_gemm<DIN, true><<<gA, 256, 0, stream>>>(Xb, Wab, adapt_b, perm, cnt, offt, h, N, D);

  // two relational layers
  dim3 gL((N + 127) / 128, LDH / 128, 1);
  for (int l = 0; l < 2; ++l) {
    const ushort* Wl = Wcat + (size_t)l * NSLOT * D * D;
    k_mfma_gemm<D, false><<<gL, 256, 0, stream>>>(h, Wl, nullptr, nullptr, nullptr, nullptr,
                                                  Hall, N, LDH);
    if (l == 0)
      k_combine<false><<<(N + 3) / 4, 256, 0, stream>>>(Hall, rowptr, epack, inv,
                                                        b_self + (size_t)l * D, h, N);
    else
      k_combine<true><<<(N + 3) / 4, 256, 0, stream>>>(Hall, rowptr, epack, inv,
                                                       b_self + (size_t)l * D, d_out, N);
  }
}

// Round 4
// 268.884 us; speedup vs baseline: 12.8335x; 1.1064x over previous
//
#include <hip/hip_runtime.h>

constexpr int NTYPES = 8;
constexpr int NREL   = 6;
constexpr int NSLOT  = 7;          // 6 relations + self
constexpr int D      = 256;
constexpr int DIN    = 512;
constexpr int LDH    = NSLOT * D;  // 1792

using short8 = __attribute__((ext_vector_type(8))) short;
using f32x4  = __attribute__((ext_vector_type(4))) float;

__device__ __forceinline__ ushort f2b(float f) {  // f32 -> bf16 RNE
  unsigned u = __float_as_uint(f);
  u += 0x7fffu + ((u >> 16) & 1u);
  return (ushort)(u >> 16);
}
__device__ __forceinline__ float b2f(unsigned bits16) {
  return __uint_as_float(bits16 << 16);
}

#define GLOAD_LDS16(g, l)                                              \
  __builtin_amdgcn_global_load_lds(                                    \
      (__attribute__((address_space(1))) void*)(g),                    \
      (__attribute__((address_space(3))) void*)(l), 16, 0, 0)

// ---------------- prep kernels ----------------
__global__ void k_cvt_bf16(const float* __restrict__ in, ushort* __restrict__ out, int n4) {
  int i = blockIdx.x * blockDim.x + threadIdx.x;
  if (i >= n4) return;
  float4 v = ((const float4*)in)[i];
  ushort4 o;
  o.x = f2b(v.x); o.y = f2b(v.y); o.z = f2b(v.z); o.w = f2b(v.w);
  ((ushort4*)out)[i] = o;
}

// Wcat[l][s][e][d] = (s<6 ? W_rel[l][s][d][e] : W_self[l][d][e]) as bf16
__global__ void k_pack_wcat(const float* __restrict__ Wrel, const float* __restrict__ Wself,
                            ushort* __restrict__ Wcat) {
  int l = blockIdx.z, s = blockIdx.y;
  int o = blockIdx.x * 256 + threadIdx.x;   // over D*D
  int e = o >> 8, d = o & 255;
  float v = (s < NREL) ? Wrel[(((size_t)l * NREL + s) * D + d) * D + e]
                       : Wself[((size_t)l * D + d) * D + e];
  Wcat[(((size_t)l * NSLOT + s) * D + e) * D + d] = f2b(v);
}

// ---- contention-free counting sort by node type (ballot-based, 3 phases) ----
__global__ void k_type_blockcnt(const int* __restrict__ ntype, int* __restrict__ blockcnt,
                                int N) {
  __shared__ int cnt[NTYPES];
  int i = blockIdx.x * 256 + threadIdx.x;
  if (threadIdx.x < NTYPES) cnt[threadIdx.x] = 0;
  __syncthreads();
  int t = (i < N) ? ntype[i] : -1;
#pragma unroll
  for (int ty = 0; ty < NTYPES; ++ty) {
    unsigned long long m = __ballot(t == ty);
    if ((threadIdx.x & 63) == 0 && m) atomicAdd(&cnt[ty], __popcll(m));
  }
  __syncthreads();
  if (threadIdx.x < NTYPES) blockcnt[blockIdx.x * NTYPES + threadIdx.x] = cnt[threadIdx.x];
}

__global__ void k_type_scan(const int* __restrict__ blockcnt, int* __restrict__ boffset,
                            int* __restrict__ cnt, int* __restrict__ offt, int nb) {
  __shared__ int tot[NTYPES];
  __shared__ int base[NTYPES];
  int t = threadIdx.x;
  if (t < NTYPES) {
    int s = 0;
    for (int b = 0; b < nb; ++b) {
      boffset[b * NTYPES + t] = s;
      s += blockcnt[b * NTYPES + t];
    }
    tot[t] = s;
    cnt[t] = s;
  }
  __syncthreads();
  if (t == 0) {
    int s = 0;
    for (int ty = 0; ty < NTYPES; ++ty) { base[ty] = s; offt[ty] = s; s += tot[ty]; }
  }
  __syncthreads();
  if (t < NTYPES)
    for (int b = 0; b < nb; ++b) boffset[b * NTYPES + t] += base[t];
}

__global__ void k_type_scatter(const int* __restrict__ ntype, const int* __restrict__ boffset,
                               int* __restrict__ perm, int N) {
  __shared__ int cur[NTYPES];
  int i = blockIdx.x * 256 + threadIdx.x;
  if (threadIdx.x < NTYPES) cur[threadIdx.x] = boffset[blockIdx.x * NTYPES + threadIdx.x];
  __syncthreads();
  int t = (i < N) ? ntype[i] : -1;
  int lane = threadIdx.x & 63;
#pragma unroll
  for (int ty = 0; ty < NTYPES; ++ty) {
    unsigned long long m = __ballot(t == ty);
    if (m) {
      int wbase = 0;
      if (lane == 0) wbase = atomicAdd(&cur[ty], __popcll(m));
      wbase = __shfl(wbase, 0);
      if (t == ty) {
        int rank = __popcll(m & ((1ull << lane) - 1ull));
        perm[wbase + rank] = i;
      }
    }
  }
}

__global__ void k_degree(const int* __restrict__ dst, int* deg, int E) {
  int i = blockIdx.x * blockDim.x + threadIdx.x;
  if (i < E) atomicAdd(&deg[dst[i]], 1);
}
__global__ void k_invdeg(const int* __restrict__ deg, float* __restrict__ inv, int N) {
  int i = blockIdx.x * blockDim.x + threadIdx.x;
  if (i < N) inv[i] = 1.0f / fmaxf((float)deg[i], 1.0f);
}

// ---------------- CSR build (3-phase scan + counting sort) ----------------
__global__ void k_scan_block(const int* __restrict__ deg, int* __restrict__ rowptr,
                             int* __restrict__ bsum, int N) {
  __shared__ int s[256];
  int i = blockIdx.x * 256 + threadIdx.x;
  int v = (i < N) ? deg[i] : 0;
  s[threadIdx.x] = v;
  __syncthreads();
  for (int o = 1; o < 256; o <<= 1) {
    int t = (threadIdx.x >= o) ? s[threadIdx.x - o] : 0;
    __syncthreads();
    s[threadIdx.x] += t;
    __syncthreads();
  }
  if (i < N) rowptr[i] = s[threadIdx.x] - v;   // exclusive within block
  if (threadIdx.x == 255) bsum[blockIdx.x] = s[255];
}
__global__ void k_scan_bsum(int* bsum, int nb) {
  if (threadIdx.x == 0) {
    int s = 0;
    for (int b = 0; b < nb; ++b) { int t = bsum[b]; bsum[b] = s; s += t; }
  }
}
__global__ void k_scan_add(int* __restrict__ rowptr, int* __restrict__ cursor,
                           const int* __restrict__ bsum, int N, int E) {
  int i = blockIdx.x * 256 + threadIdx.x;
  if (i < N) { int r = rowptr[i] + bsum[blockIdx.x]; rowptr[i] = r; cursor[i] = r; }
  if (i == 0) rowptr[N] = E;
}
__global__ void k_sortedges(const int* __restrict__ src, const int* __restrict__ dst,
                            const int* __restrict__ et, int* cursor,
                            int* __restrict__ epack, int E) {
  int e = blockIdx.x * 256 + threadIdx.x;
  if (e < E) {
    int pos = atomicAdd(&cursor[dst[e]], 1);
    epack[pos] = (src[e] << 3) | et[e];
  }
}

// ---------------- MFMA GEMM (2-phase double-buffered) ----------------
// C[m][n] = sum_k A[m][k] * B[n][k]   (B stored row-per-output-col, k-contiguous)
// 128x128 tile, 4 waves (2x2 of 64x64), BK=32, bf16 in / f32 acc / bf16 out.
// K-loop: STAGE(next, buf^1) issued BEFORE ds_read+MFMA(buf); vmcnt(0)+s_barrier
// AFTER MFMA so the prefetch's HBM latency hides under compute (T3-min recipe).
template <int KDIM, bool ADAPT>
__global__ __launch_bounds__(256, 2)
void k_mfma_gemm(const ushort* __restrict__ A, const ushort* __restrict__ B,
                 const float* __restrict__ bias,
                 const int* __restrict__ perm, const int* __restrict__ cnt,
                 const int* __restrict__ off,
                 ushort* __restrict__ Cout, int N, int ldC) {
  int mcnt = N;
  const int* permt = nullptr;
  const ushort* Bt = B;
  const float* biast = bias;
  if (ADAPT) {
    int t = blockIdx.z;
    mcnt = cnt[t];
    permt = perm + off[t];
    Bt = B + (size_t)t * D * KDIM;
    biast = bias + t * D;
  }
  const int m0 = blockIdx.x * 128;
  if (m0 >= mcnt) return;
  const int n0 = blockIdx.y * 128;

  __shared__ ushort SM[2][2][128 * 32];   // [buf][A=0/B=1][row*32+k]

  const int tid  = threadIdx.x;
  const int lane = tid & 63;
  const int w    = tid >> 6;
  const int wr   = (w >> 1) * 64;
  const int wc   = (w & 1) * 64;

  // staging: 8 x 1KB calls per matrix; wave w does calls {w, w+4}.
  // XOR swizzle: content slot' = slot ^ ((row>>1)&3), applied to GLOBAL source
  // (LDS dest stays linear — global_load_lds requirement), undone at ds_read.
  const int sr0 = w * 16 + (lane >> 2);
  const int sr1 = (w + 4) * 16 + (lane >> 2);
  const int sl0 = (lane & 3) ^ ((sr0 >> 1) & 3);
  const int sl1 = (lane & 3) ^ ((sr1 >> 1) & 3);

  int ga0, ga1;
  if (ADAPT) {
    ga0 = permt[min(m0 + sr0, mcnt - 1)];
    ga1 = permt[min(m0 + sr1, mcnt - 1)];
  } else {
    ga0 = min(m0 + sr0, N - 1);
    ga1 = min(m0 + sr1, N - 1);
  }
  const ushort* gA0 = A + (size_t)ga0 * KDIM + sl0 * 8;
  const ushort* gA1 = A + (size_t)ga1 * KDIM + sl1 * 8;
  const ushort* gB0 = Bt + (size_t)(n0 + sr0) * KDIM + sl0 * 8;
  const ushort* gB1 = Bt + (size_t)(n0 + sr1) * KDIM + sl1 * 8;

  const int lo0 = w * 512;          // 512 shorts = 1KB per call
  const int lo1 = (w + 4) * 512;

  auto STAGE = [&](int k0, int buf) {
    GLOAD_LDS16(gA0 + k0, &SM[buf][0][lo0]);
    GLOAD_LDS16(gA1 + k0, &SM[buf][0][lo1]);
    GLOAD_LDS16(gB0 + k0, &SM[buf][1][lo0]);
    GLOAD_LDS16(gB1 + k0, &SM[buf][1][lo1]);
  };

  f32x4 acc[4][4] = {};

  const int r15 = lane & 15;
  const int g   = lane >> 4;
  const int gsw = g ^ ((r15 >> 1) & 3);  // swizzled k-slot for frag reads

  // prologue
  STAGE(0, 0);
  asm volatile("s_waitcnt vmcnt(0)" ::: "memory");
  __builtin_amdgcn_s_barrier();

  constexpr int NT = KDIM / 32;
  int curb = 0;
#pragma unroll
  for (int t = 0; t < NT; ++t) {
    if (t + 1 < NT) STAGE((t + 1) * 32, curb ^ 1);   // prefetch next tile

    short8 af[4], bf[4];
#pragma unroll
    for (int i = 0; i < 4; ++i) {
      int r = wr + i * 16 + r15;
      af[i] = *(const short8*)(&SM[curb][0][r * 32 + gsw * 8]);
      int c = wc + i * 16 + r15;
      bf[i] = *(const short8*)(&SM[curb][1][c * 32 + gsw * 8]);
    }
#pragma unroll
    for (int i = 0; i < 4; ++i)
#pragma unroll
      for (int j = 0; j < 4; ++j)
        acc[i][j] = __builtin_amdgcn_mfma_f32_16x16x32_bf16(af[i], bf[j], acc[i][j], 0, 0, 0);

    asm volatile("s_waitcnt vmcnt(0)" ::: "memory");  // prefetch landed
    __builtin_amdgcn_s_barrier();                      // all waves done reading curb
    curb ^= 1;
  }

  // C/D layout (m89-verified): col = lane&15, row = (lane>>4)*4 + reg
  if (ADAPT) {
#pragma unroll
    for (int i = 0; i < 4; ++i) {
#pragma unroll
      for (int q = 0; q < 4; ++q) {
        int rl = m0 + wr + i * 16 + (lane >> 4) * 4 + q;
        if (rl < mcnt) {
          int node = permt[rl];
#pragma unroll
          for (int j = 0; j < 4; ++j) {
            int n = n0 + wc + j * 16 + (lane & 15);
            Cout[(size_t)node * ldC + n] = f2b(tanhf(acc[i][j][q] + biast[n]));
          }
        }
      }
    }
  } else {
#pragma unroll
    for (int i = 0; i < 4; ++i) {
#pragma unroll
      for (int q = 0; q < 4; ++q) {
        int m = m0 + wr + i * 16 + (lane >> 4) * 4 + q;
        if (m < N) {
#pragma unroll
          for (int j = 0; j < 4; ++j) {
            int n = n0 + wc + j * 16 + (lane & 15);
            Cout[(size_t)m * ldC + n] = f2b(acc[i][j][q]);
          }
        }
      }
    }
  }
}

// ---------------- CSR gather-combine ----------------
// out[v] = relu( (sum_{e in in(v)} Hall[src_e][rel_e*256 + :]) * inv[v]
//                + Hall[v][6*256 + :] + bias )
// one wave per node, lane owns 4 channels; edge loop unrolled x4 so 4
// independent L2/L3 gathers are in flight per wave.
template <bool LAST>
__global__ void k_combine(const ushort* __restrict__ Hall, const int* __restrict__ rowptr,
                          const int* __restrict__ epack, const float* __restrict__ invd,
                          const float* __restrict__ bias, void* __restrict__ outp, int N) {
  int v = blockIdx.x * 4 + (threadIdx.x >> 6);
  if (v >= N) return;
  int lane = threadIdx.x & 63;
  int e0 = rowptr[v], e1 = rowptr[v + 1];
  float a0 = 0.f, a1 = 0.f, a2 = 0.f, a3 = 0.f;
  int e = e0;
  for (; e + 4 <= e1; e += 4) {
    int p0 = epack[e], p1 = epack[e + 1], p2 = epack[e + 2], p3 = epack[e + 3];
    const uint2 u0 = *(const uint2*)(Hall + (size_t)(p0 >> 3) * LDH + (p0 & 7) * D + lane * 4);
    const uint2 u1 = *(const uint2*)(Hall + (size_t)(p1 >> 3) * LDH + (p1 & 7) * D + lane * 4);
    const uint2 u2 = *(const uint2*)(Hall + (size_t)(p2 >> 3) * LDH + (p2 & 7) * D + lane * 4);
    const uint2 u3 = *(const uint2*)(Hall + (size_t)(p3 >> 3) * LDH + (p3 & 7) * D + lane * 4);
    a0 += b2f(u0.x & 0xffffu) + b2f(u1.x & 0xffffu) + b2f(u2.x & 0xffffu) + b2f(u3.x & 0xffffu);
    a1 += __uint_as_float(u0.x & 0xffff0000u) + __uint_as_float(u1.x & 0xffff0000u)
        + __uint_as_float(u2.x & 0xffff0000u) + __uint_as_float(u3.x & 0xffff0000u);
    a2 += b2f(u0.y & 0xffffu) + b2f(u1.y & 0xffffu) + b2f(u2.y & 0xffffu) + b2f(u3.y & 0xffffu);
    a3 += __uint_as_float(u0.y & 0xffff0000u) + __uint_as_float(u1.y & 0xffff0000u)
        + __uint_as_float(u2.y & 0xffff0000u) + __uint_as_float(u3.y & 0xffff0000u);
  }
  for (; e < e1; ++e) {
    int p = epack[e];
    const uint2 u = *(const uint2*)(Hall + (size_t)(p >> 3) * LDH + (p & 7) * D + lane * 4);
    a0 += b2f(u.x & 0xffffu);
    a1 += __uint_as_float(u.x & 0xffff0000u);
    a2 += b2f(u.y & 0xffffu);
    a3 += __uint_as_float(u.y & 0xffff0000u);
  }
  const uint2 s = *(const uint2*)(Hall + (size_t)v * LDH + NREL * D + lane * 4);
  float iv = invd[v];
  const float4 b4 = *(const float4*)(bias + lane * 4);
  float o0 = fmaxf(fmaf(a0, iv, b2f(s.x & 0xffffu)) + b4.x, 0.f);
  float o1 = fmaxf(fmaf(a1, iv, __uint_as_float(s.x & 0xffff0000u)) + b4.y, 0.f);
  float o2 = fmaxf(fmaf(a2, iv, b2f(s.y & 0xffffu)) + b4.z, 0.f);
  float o3 = fmaxf(fmaf(a3, iv, __uint_as_float(s.y & 0xffff0000u)) + b4.w, 0.f);
  if (LAST) {
    float4 o; o.x = o0; o.y = o1; o.z = o2; o.w = o3;
    ((float4*)outp)[(size_t)v * 64 + lane] = o;
  } else {
    ushort4 o; o.x = f2b(o0); o.y = f2b(o1); o.z = f2b(o2); o.w = f2b(o3);
    ((ushort4*)outp)[(size_t)v * 64 + lane] = o;
  }
}

extern "C" void kernel_launch(void* const* d_in, const int* in_sizes, int n_in,
                              void* d_out, int out_size, void* d_ws, size_t ws_size,
                              hipStream_t stream) {
  const float* X       = (const float*)d_in[0];
  const int*   ntype   = (const int*)d_in[1];
  const int*   eidx    = (const int*)d_in[2];
  const int*   etype   = (const int*)d_in[3];
  const float* adapt_W = (const float*)d_in[5];
  const float* adapt_b = (const float*)d_in[6];
  const float* W_rel   = (const float*)d_in[7];
  const float* W_self  = (const float*)d_in[8];
  const float* b_self  = (const float*)d_in[9];

  const int N = in_sizes[1];
  const int E = in_sizes[3];
  const int* src = eidx;
  const int* dst = eidx + E;

  char* ws = (char*)d_ws;
  size_t o = 0;
  auto alloc = [&](size_t bytes) { void* p = ws + o; o += (bytes + 255) & ~255ull; return p; };

  ushort* Hall  = (ushort*)alloc((size_t)N * LDH * 2);  // 71.7 MB; also aliases Xb
  ushort* Xb    = Hall;                                  // Xb (20.5 MB) dead before Hall written
  ushort* h     = (ushort*)alloc((size_t)N * D * 2);
  ushort* Wab   = (ushort*)alloc((size_t)NTYPES * D * DIN * 2);
  ushort* Wcat  = (ushort*)alloc((size_t)2 * NSLOT * D * D * 2);
  int*   deg    = (int*)alloc((size_t)N * 4);
  float* inv    = (float*)alloc((size_t)N * 4);
  int*   perm   = (int*)alloc((size_t)N * 4);
  int*   rowptr = (int*)alloc((size_t)(N + 1) * 4);
  int*   cursor = (int*)alloc((size_t)N * 4);
  int*   epack  = (int*)alloc((size_t)E * 4);
  int*   bsum   = (int*)alloc(1024 * 4);
  int*   blockcnt = (int*)alloc((size_t)1024 * NTYPES * 4);
  int*   boffset  = (int*)alloc((size_t)1024 * NTYPES * 4);
  int*   cnt    = (int*)alloc(NTYPES * 4);
  int*   offt   = (int*)alloc(NTYPES * 4);

  hipMemsetAsync(deg, 0, (size_t)N * 4, stream);

  const int thr = 256;
  const int nbN = (N + thr - 1) / thr;
  const int nbE = (E + thr - 1) / thr;

  // bf16 conversions / weight packing
  k_cvt_bf16<<<(N * DIN / 4 + thr - 1) / thr, thr, 0, stream>>>(X, Xb, N * DIN / 4);
  k_cvt_bf16<<<(NTYPES * D * DIN / 4 + thr - 1) / thr, thr, 0, stream>>>(adapt_W, Wab,
                                                                          NTYPES * D * DIN / 4);
  dim3 gW(D * D / 256, NSLOT, 2);
  k_pack_wcat<<<gW, 256, 0, stream>>>(W_rel, W_self, Wcat);

  // type sort (ballot-based, contention-free) + degrees
  k_type_blockcnt<<<nbN, thr, 0, stream>>>(ntype, blockcnt, N);
  k_type_scan<<<1, 64, 0, stream>>>(blockcnt, boffset, cnt, offt, nbN);
  k_type_scatter<<<nbN, thr, 0, stream>>>(ntype, boffset, perm, N);
  k_degree<<<nbE, thr, 0, stream>>>(dst, deg, E);
  k_invdeg<<<nbN, thr, 0, stream>>>(deg, inv, N);

  // CSR by dst
  k_scan_block<<<nbN, 256, 0, stream>>>(deg, rowptr, bsum, N);
  k_scan_bsum<<<1, 64, 0, stream>>>(bsum, nbN);
  k_scan_add<<<nbN, 256, 0, stream>>>(rowptr, cursor, bsum, N, E);
  k_sortedges<<<nbE, 256, 0, stream>>>(src, dst, etype, cursor, epack, E);

  // adaptation: h = tanh(X @ W_t^T + b_t), bf16 out
  dim3 gA((N + 127) / 128, D / 128, NTYPES);
  k_mfma_gemm<DIN, true><<<gA, 256, 0, stream>>>(Xb, Wab, adapt_b, perm, cnt, offt, h, N, D);

  // two relational layers
  dim3 gL((N + 127) / 128, LDH / 128, 1);
  for (int l = 0; l < 2; ++l) {
    const ushort* Wl = Wcat + (size_t)l * NSLOT * D * D;
    k_mfma_gemm<D, false><<<gL, 256, 0, stream>>>(h, Wl, nullptr, nullptr, nullptr, nullptr,
                                                  Hall, N, LDH);
    if (l == 0)
      k_combine<false><<<(N + 3) / 4, 256, 0, stream>>>(Hall, rowptr, epack, inv,
                                                        b_self + (size_t)l * D, h, N);
    else
      k_combine<true><<<(N + 3) / 4, 256, 0, stream>>>(Hall, rowptr, epack, inv,
                                                       b_self + (size_t)l * D, d_out, N);
  }
}

// Round 5
// 260.172 us; speedup vs baseline: 13.2632x; 1.0335x over previous
//
#include <hip/hip_runtime.h>

constexpr int NTYPES = 8;
constexpr int NREL   = 6;
constexpr int NSLOT  = 7;          // 6 relations + self
constexpr int D      = 256;
constexpr int DIN    = 512;
constexpr int LDH    = NSLOT * D;  // 1792

using short8 = __attribute__((ext_vector_type(8))) short;
using f32x4  = __attribute__((ext_vector_type(4))) float;

__device__ __forceinline__ ushort f2b(float f) {  // f32 -> bf16 RNE
  unsigned u = __float_as_uint(f);
  u += 0x7fffu + ((u >> 16) & 1u);
  return (ushort)(u >> 16);
}
__device__ __forceinline__ float b2f(unsigned bits16) {
  return __uint_as_float(bits16 << 16);
}

#define GLOAD_LDS16(g, l)                                              \
  __builtin_amdgcn_global_load_lds(                                    \
      (__attribute__((address_space(1))) void*)(g),                    \
      (__attribute__((address_space(3))) void*)(l), 16, 0, 0)

// ---------------- prep kernels ----------------
__global__ void k_cvt_bf16(const float* __restrict__ in, ushort* __restrict__ out, int n4) {
  int i = blockIdx.x * blockDim.x + threadIdx.x;
  if (i >= n4) return;
  float4 v = ((const float4*)in)[i];
  ushort4 o;
  o.x = f2b(v.x); o.y = f2b(v.y); o.z = f2b(v.z); o.w = f2b(v.w);
  ((ushort4*)out)[i] = o;
}

// Wcat[l][s][e][d] = (s<6 ? W_rel[l][s][d][e] : W_self[l][d][e]) as bf16
__global__ void k_pack_wcat(const float* __restrict__ Wrel, const float* __restrict__ Wself,
                            ushort* __restrict__ Wcat) {
  int l = blockIdx.z, s = blockIdx.y;
  int o = blockIdx.x * 256 + threadIdx.x;   // over D*D
  int e = o >> 8, d = o & 255;
  float v = (s < NREL) ? Wrel[(((size_t)l * NREL + s) * D + d) * D + e]
                       : Wself[((size_t)l * D + d) * D + e];
  Wcat[(((size_t)l * NSLOT + s) * D + e) * D + d] = f2b(v);
}

// ---- contention-free counting sort by node type (ballot-based, 3 phases) ----
__global__ void k_type_blockcnt(const int* __restrict__ ntype, int* __restrict__ blockcnt,
                                int N) {
  __shared__ int cnt[NTYPES];
  int i = blockIdx.x * 256 + threadIdx.x;
  if (threadIdx.x < NTYPES) cnt[threadIdx.x] = 0;
  __syncthreads();
  int t = (i < N) ? ntype[i] : -1;
#pragma unroll
  for (int ty = 0; ty < NTYPES; ++ty) {
    unsigned long long m = __ballot(t == ty);
    if ((threadIdx.x & 63) == 0 && m) atomicAdd(&cnt[ty], __popcll(m));
  }
  __syncthreads();
  if (threadIdx.x < NTYPES) blockcnt[blockIdx.x * NTYPES + threadIdx.x] = cnt[threadIdx.x];
}

__global__ void k_type_scan(const int* __restrict__ blockcnt, int* __restrict__ boffset,
                            int* __restrict__ cnt, int* __restrict__ offt, int nb) {
  __shared__ int tot[NTYPES];
  __shared__ int base[NTYPES];
  int t = threadIdx.x;
  if (t < NTYPES) {
    int s = 0;
    for (int b = 0; b < nb; ++b) {
      boffset[b * NTYPES + t] = s;
      s += blockcnt[b * NTYPES + t];
    }
    tot[t] = s;
    cnt[t] = s;
  }
  __syncthreads();
  if (t == 0) {
    int s = 0;
    for (int ty = 0; ty < NTYPES; ++ty) { base[ty] = s; offt[ty] = s; s += tot[ty]; }
  }
  __syncthreads();
  if (t < NTYPES)
    for (int b = 0; b < nb; ++b) boffset[b * NTYPES + t] += base[t];
}

__global__ void k_type_scatter(const int* __restrict__ ntype, const int* __restrict__ boffset,
                               int* __restrict__ perm, int N) {
  __shared__ int cur[NTYPES];
  int i = blockIdx.x * 256 + threadIdx.x;
  if (threadIdx.x < NTYPES) cur[threadIdx.x] = boffset[blockIdx.x * NTYPES + threadIdx.x];
  __syncthreads();
  int t = (i < N) ? ntype[i] : -1;
  int lane = threadIdx.x & 63;
#pragma unroll
  for (int ty = 0; ty < NTYPES; ++ty) {
    unsigned long long m = __ballot(t == ty);
    if (m) {
      int wbase = 0;
      if (lane == 0) wbase = atomicAdd(&cur[ty], __popcll(m));
      wbase = __shfl(wbase, 0);
      if (t == ty) {
        int rank = __popcll(m & ((1ull << lane) - 1ull));
        perm[wbase + rank] = i;
      }
    }
  }
}

__global__ void k_degree(const int* __restrict__ dst, int* deg, int E) {
  int i = blockIdx.x * blockDim.x + threadIdx.x;
  if (i < E) atomicAdd(&deg[dst[i]], 1);
}
__global__ void k_invdeg(const int* __restrict__ deg, float* __restrict__ inv, int N) {
  int i = blockIdx.x * blockDim.x + threadIdx.x;
  if (i < N) inv[i] = 1.0f / fmaxf((float)deg[i], 1.0f);
}

// ---------------- CSR build (3-phase scan + counting sort) ----------------
__global__ void k_scan_block(const int* __restrict__ deg, int* __restrict__ rowptr,
                             int* __restrict__ bsum, int N) {
  __shared__ int s[256];
  int i = blockIdx.x * 256 + threadIdx.x;
  int v = (i < N) ? deg[i] : 0;
  s[threadIdx.x] = v;
  __syncthreads();
  for (int o = 1; o < 256; o <<= 1) {
    int t = (threadIdx.x >= o) ? s[threadIdx.x - o] : 0;
    __syncthreads();
    s[threadIdx.x] += t;
    __syncthreads();
  }
  if (i < N) rowptr[i] = s[threadIdx.x] - v;   // exclusive within block
  if (threadIdx.x == 255) bsum[blockIdx.x] = s[255];
}
__global__ void k_scan_bsum(int* bsum, int nb) {
  if (threadIdx.x == 0) {
    int s = 0;
    for (int b = 0; b < nb; ++b) { int t = bsum[b]; bsum[b] = s; s += t; }
  }
}
__global__ void k_scan_add(int* __restrict__ rowptr, int* __restrict__ cursor,
                           const int* __restrict__ bsum, int N, int E) {
  int i = blockIdx.x * 256 + threadIdx.x;
  if (i < N) { int r = rowptr[i] + bsum[blockIdx.x]; rowptr[i] = r; cursor[i] = r; }
  if (i == 0) rowptr[N] = E;
}
__global__ void k_sortedges(const int* __restrict__ src, const int* __restrict__ dst,
                            const int* __restrict__ et, int* cursor,
                            int* __restrict__ epack, int E) {
  int e = blockIdx.x * 256 + threadIdx.x;
  if (e < E) {
    int pos = atomicAdd(&cursor[dst[e]], 1);
    epack[pos] = (src[e] << 3) | et[e];
  }
}

// ---------------- MFMA GEMM (templated tile, 2-phase double-buffered) ----------------
// C[m][n] = sum_k A[m][k] * B[n][k]   (B stored row-per-output-col, k-contiguous)
// BMxBN tile, 4 waves (2x2), BK=32, bf16 in / f32 acc / bf16 out.
// ADAPT: A-rows gathered via type-sorted perm, B = per-type W, epilogue tanh(+bias).
// Small tile (64x64) -> many blocks -> TLP hides memory latency (round-4 lesson:
// depth-1 dbuf cannot hide ~900cyc under ~170cyc compute; co-resident waves can).
template <int BM, int BN, int KDIM, bool ADAPT, int OCC>
__global__ __launch_bounds__(256, OCC)
void k_mfma_gemm(const ushort* __restrict__ A, const ushort* __restrict__ B,
                 const float* __restrict__ bias,
                 const int* __restrict__ perm, const int* __restrict__ cnt,
                 const int* __restrict__ off,
                 ushort* __restrict__ Cout, int N, int ldC) {
  static_assert(BM == BN, "square tiles only");
  int mcnt = N;
  const int* permt = nullptr;
  const ushort* Bt = B;
  const float* biast = bias;
  if (ADAPT) {
    int t = blockIdx.z;
    mcnt = cnt[t];
    permt = perm + off[t];
    Bt = B + (size_t)t * D * KDIM;
    biast = bias + t * D;
  }
  const int m0 = blockIdx.x * BM;
  if (m0 >= mcnt) return;
  const int n0 = blockIdx.y * BN;

  __shared__ ushort SM[2][2][BM * 32];   // [buf][A=0/B=1][row*32+k]

  const int tid  = threadIdx.x;
  const int lane = tid & 63;
  const int w    = tid >> 6;
  constexpr int FR = BM / 32;            // 16x16 frags per wave (rows)
  constexpr int FC = BN / 32;
  const int wr   = (w >> 1) * (BM / 2);
  const int wc   = (w & 1) * (BN / 2);

  // staging: (BM/16) x 1KB calls per matrix; wave w does calls {w, w+4, ...}.
  // call c covers LDS rows [16c,16c+16); lane -> row 16c+(lane>>2), slot lane&3.
  // XOR swizzle: content slot' = slot ^ ((row>>1)&3), applied to GLOBAL source
  // (LDS dest stays linear — global_load_lds requirement), undone at ds_read.
  constexpr int PW = BM / 16 / 4;        // calls per wave per matrix (1 or 2)
  const ushort* gA[PW];
  const ushort* gB[PW];
  int lo[PW];
#pragma unroll
  for (int u = 0; u < PW; ++u) {
    const int c  = w + u * 4;
    const int r  = c * 16 + (lane >> 2);
    const int sl = (lane & 3) ^ ((r >> 1) & 3);
    int ga;
    if (ADAPT) ga = permt[min(m0 + r, mcnt - 1)];
    else       ga = min(m0 + r, N - 1);
    gA[u] = A + (size_t)ga * KDIM + sl * 8;
    gB[u] = Bt + (size_t)(n0 + r) * KDIM + sl * 8;
    lo[u] = c * 512;                     // shorts
  }

  auto STAGE = [&](int k0, int buf) {
#pragma unroll
    for (int u = 0; u < PW; ++u) {
      GLOAD_LDS16(gA[u] + k0, &SM[buf][0][lo[u]]);
      GLOAD_LDS16(gB[u] + k0, &SM[buf][1][lo[u]]);
    }
  };

  f32x4 acc[FR][FC] = {};

  const int r15 = lane & 15;
  const int g   = lane >> 4;
  const int gsw = g ^ ((r15 >> 1) & 3);  // swizzled k-slot for frag reads

  // prologue
  STAGE(0, 0);
  asm volatile("s_waitcnt vmcnt(0)" ::: "memory");
  __builtin_amdgcn_s_barrier();

  constexpr int NT = KDIM / 32;
  int curb = 0;
#pragma unroll
  for (int t = 0; t < NT; ++t) {
    if (t + 1 < NT) STAGE((t + 1) * 32, curb ^ 1);   // prefetch next tile

    short8 af[FR], bf[FC];
#pragma unroll
    for (int i = 0; i < FR; ++i)
      af[i] = *(const short8*)(&SM[curb][0][(wr + i * 16 + r15) * 32 + gsw * 8]);
#pragma unroll
    for (int j = 0; j < FC; ++j)
      bf[j] = *(const short8*)(&SM[curb][1][(wc + j * 16 + r15) * 32 + gsw * 8]);
#pragma unroll
    for (int i = 0; i < FR; ++i)
#pragma unroll
      for (int j = 0; j < FC; ++j)
        acc[i][j] = __builtin_amdgcn_mfma_f32_16x16x32_bf16(af[i], bf[j], acc[i][j], 0, 0, 0);

    asm volatile("s_waitcnt vmcnt(0)" ::: "memory");  // prefetch landed
    __builtin_amdgcn_s_barrier();                      // all waves done reading curb
    curb ^= 1;
  }

  // C/D layout (m89-verified): col = lane&15, row = (lane>>4)*4 + reg
  if (ADAPT) {
#pragma unroll
    for (int i = 0; i < FR; ++i) {
#pragma unroll
      for (int q = 0; q < 4; ++q) {
        int rl = m0 + wr + i * 16 + (lane >> 4) * 4 + q;
        if (rl < mcnt) {
          int node = permt[rl];
#pragma unroll
          for (int j = 0; j < FC; ++j) {
            int n = n0 + wc + j * 16 + (lane & 15);
            Cout[(size_t)node * ldC + n] = f2b(tanhf(acc[i][j][q] + biast[n]));
          }
        }
      }
    }
  } else {
#pragma unroll
    for (int i = 0; i < FR; ++i) {
#pragma unroll
      for (int q = 0; q < 4; ++q) {
        int m = m0 + wr + i * 16 + (lane >> 4) * 4 + q;
        if (m < N) {
#pragma unroll
          for (int j = 0; j < FC; ++j) {
            int n = n0 + wc + j * 16 + (lane & 15);
            Cout[(size_t)m * ldC + n] = f2b(acc[i][j][q]);
          }
        }
      }
    }
  }
}

// ---------------- CSR gather-combine ----------------
// out[v] = relu( (sum_{e in in(v)} Hall[src_e][rel_e*256 + :]) * inv[v]
//                + Hall[v][6*256 + :] + bias )
// one wave per node, lane owns 4 channels; edge loop unrolled x4 so 4
// independent L2/L3 gathers are in flight per wave.
template <bool LAST>
__global__ void k_combine(const ushort* __restrict__ Hall, const int* __restrict__ rowptr,
                          const int* __restrict__ epack, const float* __restrict__ invd,
                          const float* __restrict__ bias, void* __restrict__ outp, int N) {
  int v = blockIdx.x * 4 + (threadIdx.x >> 6);
  if (v >= N) return;
  int lane = threadIdx.x & 63;
  int e0 = rowptr[v], e1 = rowptr[v + 1];
  float a0 = 0.f, a1 = 0.f, a2 = 0.f, a3 = 0.f;
  int e = e0;
  for (; e + 4 <= e1; e += 4) {
    int p0 = epack[e], p1 = epack[e + 1], p2 = epack[e + 2], p3 = epack[e + 3];
    const uint2 u0 = *(const uint2*)(Hall + (size_t)(p0 >> 3) * LDH + (p0 & 7) * D + lane * 4);
    const uint2 u1 = *(const uint2*)(Hall + (size_t)(p1 >> 3) * LDH + (p1 & 7) * D + lane * 4);
    const uint2 u2 = *(const uint2*)(Hall + (size_t)(p2 >> 3) * LDH + (p2 & 7) * D + lane * 4);
    const uint2 u3 = *(const uint2*)(Hall + (size_t)(p3 >> 3) * LDH + (p3 & 7) * D + lane * 4);
    a0 += b2f(u0.x & 0xffffu) + b2f(u1.x & 0xffffu) + b2f(u2.x & 0xffffu) + b2f(u3.x & 0xffffu);
    a1 += __uint_as_float(u0.x & 0xffff0000u) + __uint_as_float(u1.x & 0xffff0000u)
        + __uint_as_float(u2.x & 0xffff0000u) + __uint_as_float(u3.x & 0xffff0000u);
    a2 += b2f(u0.y & 0xffffu) + b2f(u1.y & 0xffffu) + b2f(u2.y & 0xffffu) + b2f(u3.y & 0xffffu);
    a3 += __uint_as_float(u0.y & 0xffff0000u) + __uint_as_float(u1.y & 0xffff0000u)
        + __uint_as_float(u2.y & 0xffff0000u) + __uint_as_float(u3.y & 0xffff0000u);
  }
  for (; e < e1; ++e) {
    int p = epack[e];
    const uint2 u = *(const uint2*)(Hall + (size_t)(p >> 3) * LDH + (p & 7) * D + lane * 4);
    a0 += b2f(u.x & 0xffffu);
    a1 += __uint_as_float(u.x & 0xffff0000u);
    a2 += b2f(u.y & 0xffffu);
    a3 += __uint_as_float(u.y & 0xffff0000u);
  }
  const uint2 s = *(const uint2*)(Hall + (size_t)v * LDH + NREL * D + lane * 4);
  float iv = invd[v];
  const float4 b4 = *(const float4*)(bias + lane * 4);
  float o0 = fmaxf(fmaf(a0, iv, b2f(s.x & 0xffffu)) + b4.x, 0.f);
  float o1 = fmaxf(fmaf(a1, iv, __uint_as_float(s.x & 0xffff0000u)) + b4.y, 0.f);
  float o2 = fmaxf(fmaf(a2, iv, b2f(s.y & 0xffffu)) + b4.z, 0.f);
  float o3 = fmaxf(fmaf(a3, iv, __uint_as_float(s.y & 0xffff0000u)) + b4.w, 0.f);
  if (LAST) {
    float4 o; o.x = o0; o.y = o1; o.z = o2; o.w = o3;
    ((float4*)outp)[(size_t)v * 64 + lane] = o;
  } else {
    ushort4 o; o.x = f2b(o0); o.y = f2b(o1); o.z = f2b(o2); o.w = f2b(o3);
    ((ushort4*)outp)[(size_t)v * 64 + lane] = o;
  }
}

extern "C" void kernel_launch(void* const* d_in, const int* in_sizes, int n_in,
                              void* d_out, int out_size, void* d_ws, size_t ws_size,
                              hipStream_t stream) {
  const float* X       = (const float*)d_in[0];
  const int*   ntype   = (const int*)d_in[1];
  const int*   eidx    = (const int*)d_in[2];
  const int*   etype   = (const int*)d_in[3];
  const float* adapt_W = (const float*)d_in[5];
  const float* adapt_b = (const float*)d_in[6];
  const float* W_rel   = (const float*)d_in[7];
  const float* W_self  = (const float*)d_in[8];
  const float* b_self  = (const float*)d_in[9];

  const int N = in_sizes[1];
  const int E = in_sizes[3];
  const int* src = eidx;
  const int* dst = eidx + E;

  char* ws = (char*)d_ws;
  size_t o = 0;
  auto alloc = [&](size_t bytes) { void* p = ws + o; o += (bytes + 255) & ~255ull; return p; };

  ushort* Hall  = (ushort*)alloc((size_t)N * LDH * 2);  // 71.7 MB; also aliases Xb
  ushort* Xb    = Hall;                                  // Xb (20.5 MB) dead before Hall written
  ushort* h     = (ushort*)alloc((size_t)N * D * 2);
  ushort* Wab   = (ushort*)alloc((size_t)NTYPES * D * DIN * 2);
  ushort* Wcat  = (ushort*)alloc((size_t)2 * NSLOT * D * D * 2);
  int*   deg    = (int*)alloc((size_t)N * 4);
  float* inv    = (float*)alloc((size_t)N * 4);
  int*   perm   = (int*)alloc((size_t)N * 4);
  int*   rowptr = (int*)alloc((size_t)(N + 1) * 4);
  int*   cursor = (int*)alloc((size_t)N * 4);
  int*   epack  = (int*)alloc((size_t)E * 4);
  int*   bsum   = (int*)alloc(1024 * 4);
  int*   blockcnt = (int*)alloc((size_t)1024 * NTYPES * 4);
  int*   boffset  = (int*)alloc((size_t)1024 * NTYPES * 4);
  int*   cnt    = (int*)alloc(NTYPES * 4);
  int*   offt   = (int*)alloc(NTYPES * 4);

  hipMemsetAsync(deg, 0, (size_t)N * 4, stream);

  const int thr = 256;
  const int nbN = (N + thr - 1) / thr;
  const int nbE = (E + thr - 1) / thr;

  // bf16 conversions / weight packing
  k_cvt_bf16<<<(N * DIN / 4 + thr - 1) / thr, thr, 0, stream>>>(X, Xb, N * DIN / 4);
  k_cvt_bf16<<<(NTYPES * D * DIN / 4 + thr - 1) / thr, thr, 0, stream>>>(adapt_W, Wab,
                                                                          NTYPES * D * DIN / 4);
  dim3 gW(D * D / 256, NSLOT, 2);
  k_pack_wcat<<<gW, 256, 0, stream>>>(W_rel, W_self, Wcat);

  // type sort (ballot-based, contention-free) + degrees
  k_type_blockcnt<<<nbN, thr, 0, stream>>>(ntype, blockcnt, N);
  k_type_scan<<<1, 64, 0, stream>>>(blockcnt, boffset, cnt, offt, nbN);
  k_type_scatter<<<nbN, thr, 0, stream>>>(ntype, boffset, perm, N);
  k_degree<<<nbE, thr, 0, stream>>>(dst, deg, E);
  k_invdeg<<<nbN, thr, 0, stream>>>(deg, inv, N);

  // CSR by dst
  k_scan_block<<<nbN, 256, 0, stream>>>(deg, rowptr, bsum, N);
  k_scan_bsum<<<1, 64, 0, stream>>>(bsum, nbN);
  k_scan_add<<<nbN, 256, 0, stream>>>(rowptr, cursor, bsum, N, E);
  k_sortedges<<<nbE, 256, 0, stream>>>(src, dst, etype, cursor, epack, E);

  // adaptation: h = tanh(X @ W_t^T + b_t), bf16 out — 64x64 tiles for TLP
  dim3 gA((N + 63) / 64, D / 64, NTYPES);
  k_mfma_gemm<64, 64, DIN, true, 6><<<gA, 256, 0, stream>>>(Xb, Wab, adapt_b, perm, cnt, offt,
                                                            h, N, D);

  // two relational layers
  dim3 gL((N + 127) / 128, LDH / 128, 1);
  for (int l = 0; l < 2; ++l) {
    const ushort* Wl = Wcat + (size_t)l * NSLOT * D * D;
    k_mfma_gemm<128, 128, D, false, 4><<<gL, 256, 0, stream>>>(h, Wl, nullptr, nullptr, nullptr,
                                                               nullptr, Hall, N, LDH);
    if (l == 0)
      k_combine<false><<<(N + 3) / 4, 256, 0, stream>>>(Hall, rowptr, epack, inv,
                                                        b_self + (size_t)l * D, h, N);
    else
      k_combine<true><<<(N + 3) / 4, 256, 0, stream>>>(Hall, rowptr, epack, inv,
                                                       b_self + (size_t)l * D, d_out, N);
  }
}

// Round 8
// 229.411 us; speedup vs baseline: 15.0416x; 1.1341x over previous
//
#include <hip/hip_runtime.h>

constexpr int NTYPES = 8;
constexpr int NREL   = 6;
constexpr int NSLOT  = 7;          // 6 relations + self
constexpr int D      = 256;
constexpr int DIN    = 512;
constexpr int LDH    = NSLOT * D;  // 1792

using short8 = __attribute__((ext_vector_type(8))) short;
using f32x4  = __attribute__((ext_vector_type(4))) float;

__device__ __forceinline__ ushort f2b(float f) {  // f32 -> bf16 RNE
  unsigned u = __float_as_uint(f);
  u += 0x7fffu + ((u >> 16) & 1u);
  return (ushort)(u >> 16);
}
__device__ __forceinline__ float b2f(unsigned bits16) {
  return __uint_as_float(bits16 << 16);
}

#define GLOAD_LDS16(g, l)                                              \
  __builtin_amdgcn_global_load_lds(                                    \
      (__attribute__((address_space(1))) void*)(g),                    \
      (__attribute__((address_space(3))) void*)(l), 16, 0, 0)

// ---------------- prep kernels ----------------
__global__ void k_cvt_bf16(const float* __restrict__ in, ushort* __restrict__ out, int n4) {
  int i = blockIdx.x * blockDim.x + threadIdx.x;
  if (i >= n4) return;
  float4 v = ((const float4*)in)[i];
  ushort4 o;
  o.x = f2b(v.x); o.y = f2b(v.y); o.z = f2b(v.z); o.w = f2b(v.w);
  ((ushort4*)out)[i] = o;
}

// Wcat[l][s][e][d] = (s<6 ? W_rel[l][s][d][e] : W_self[l][d][e]) as bf16
__global__ void k_pack_wcat(const float* __restrict__ Wrel, const float* __restrict__ Wself,
                            ushort* __restrict__ Wcat) {
  int l = blockIdx.z, s = blockIdx.y;
  int o = blockIdx.x * 256 + threadIdx.x;   // over D*D
  int e = o >> 8, d = o & 255;
  float v = (s < NREL) ? Wrel[(((size_t)l * NREL + s) * D + d) * D + e]
                       : Wself[((size_t)l * D + d) * D + e];
  Wcat[(((size_t)l * NSLOT + s) * D + e) * D + d] = f2b(v);
}

// ---- contention-free counting sort by node type (ballot-based, 3 phases) ----
__global__ void k_type_blockcnt(const int* __restrict__ ntype, int* __restrict__ blockcnt,
                                int N) {
  __shared__ int cnt[NTYPES];
  int i = blockIdx.x * 256 + threadIdx.x;
  if (threadIdx.x < NTYPES) cnt[threadIdx.x] = 0;
  __syncthreads();
  int t = (i < N) ? ntype[i] : -1;
#pragma unroll
  for (int ty = 0; ty < NTYPES; ++ty) {
    unsigned long long m = __ballot(t == ty);
    if ((threadIdx.x & 63) == 0 && m) atomicAdd(&cnt[ty], __popcll(m));
  }
  __syncthreads();
  if (threadIdx.x < NTYPES) blockcnt[blockIdx.x * NTYPES + threadIdx.x] = cnt[threadIdx.x];
}

__global__ void k_type_scan(const int* __restrict__ blockcnt, int* __restrict__ boffset,
                            int* __restrict__ cnt, int* __restrict__ offt, int nb) {
  __shared__ int tot[NTYPES];
  __shared__ int base[NTYPES];
  int t = threadIdx.x;
  if (t < NTYPES) {
    int s = 0;
    for (int b = 0; b < nb; ++b) {
      boffset[b * NTYPES + t] = s;
      s += blockcnt[b * NTYPES + t];
    }
    tot[t] = s;
    cnt[t] = s;
  }
  __syncthreads();
  if (t == 0) {
    int s = 0;
    for (int ty = 0; ty < NTYPES; ++ty) { base[ty] = s; offt[ty] = s; s += tot[ty]; }
  }
  __syncthreads();
  if (t < NTYPES)
    for (int b = 0; b < nb; ++b) boffset[b * NTYPES + t] += base[t];
}

__global__ void k_type_scatter(const int* __restrict__ ntype, const int* __restrict__ boffset,
                               int* __restrict__ perm, int N) {
  __shared__ int cur[NTYPES];
  int i = blockIdx.x * 256 + threadIdx.x;
  if (threadIdx.x < NTYPES) cur[threadIdx.x] = boffset[blockIdx.x * NTYPES + threadIdx.x];
  __syncthreads();
  int t = (i < N) ? ntype[i] : -1;
  int lane = threadIdx.x & 63;
#pragma unroll
  for (int ty = 0; ty < NTYPES; ++ty) {
    unsigned long long m = __ballot(t == ty);
    if (m) {
      int wbase = 0;
      if (lane == 0) wbase = atomicAdd(&cur[ty], __popcll(m));
      wbase = __shfl(wbase, 0);
      if (t == ty) {
        int rank = __popcll(m & ((1ull << lane) - 1ull));
        perm[wbase + rank] = i;
      }
    }
  }
}

__global__ void k_degree(const int* __restrict__ dst, int* deg, int E) {
  int i = blockIdx.x * blockDim.x + threadIdx.x;
  if (i < E) atomicAdd(&deg[dst[i]], 1);
}
__global__ void k_invdeg(const int* __restrict__ deg, float* __restrict__ inv, int N) {
  int i = blockIdx.x * blockDim.x + threadIdx.x;
  if (i < N) inv[i] = 1.0f / fmaxf((float)deg[i], 1.0f);
}

// ---------------- CSR build (3-phase scan + counting sort) ----------------
__global__ void k_scan_block(const int* __restrict__ deg, int* __restrict__ rowptr,
                             int* __restrict__ bsum, int N) {
  __shared__ int s[256];
  int i = blockIdx.x * 256 + threadIdx.x;
  int v = (i < N) ? deg[i] : 0;
  s[threadIdx.x] = v;
  __syncthreads();
  for (int o = 1; o < 256; o <<= 1) {
    int t = (threadIdx.x >= o) ? s[threadIdx.x - o] : 0;
    __syncthreads();
    s[threadIdx.x] += t;
    __syncthreads();
  }
  if (i < N) rowptr[i] = s[threadIdx.x] - v;   // exclusive within block
  if (threadIdx.x == 255) bsum[blockIdx.x] = s[255];
}
__global__ void k_scan_bsum(int* bsum, int nb) {
  if (threadIdx.x == 0) {
    int s = 0;
    for (int b = 0; b < nb; ++b) { int t = bsum[b]; bsum[b] = s; s += t; }
  }
}
__global__ void k_scan_add(int* __restrict__ rowptr, int* __restrict__ cursor,
                           const int* __restrict__ bsum, int N, int E) {
  int i = blockIdx.x * 256 + threadIdx.x;
  if (i < N) { int r = rowptr[i] + bsum[blockIdx.x]; rowptr[i] = r; cursor[i] = r; }
  if (i == 0) rowptr[N] = E;
}
__global__ void k_sortedges(const int* __restrict__ src, const int* __restrict__ dst,
                            const int* __restrict__ et, int* cursor,
                            int* __restrict__ epack, int E) {
  int e = blockIdx.x * 256 + threadIdx.x;
  if (e < E) {
    int pos = atomicAdd(&cursor[dst[e]], 1);
    epack[pos] = (src[e] << 3) | et[e];
  }
}

// ---------------- MFMA GEMM (1D swizzled grid, LDS-staged epilogue) -------------
// C[m][n] = sum_k A[m][k] * B[n][k]   (B stored row-per-output-col, k-contiguous)
// BMxBN tile, 4 waves (2x2), BK=32, bf16 in / f32 acc / bf16 out.
// 1D grid, n-tile fastest, bijective XCD swizzle (T1/m204).
// ROUND-8 FIX: K-loop barriers are REAL __syncthreads() (IR memory fence +
// vmcnt/lgkmcnt drain + s_barrier — the verified m97 pattern). Raw s_barrier
// is IntrNoMem at LLVM level: the next iteration's global_load_lds could be
// scheduled between the vmcnt asm and the barrier, overwriting the buffer
// other waves were still reading. That timing-dependent race was round-6's
// absmax failure and round-7's tripwire divergence.
template <int BM, int BN, int NTN, int KDIM, bool ADAPT, int OCC>
__global__ __launch_bounds__(256, OCC)
void k_mfma_gemm(const ushort* __restrict__ A, const ushort* __restrict__ B,
                 const float* __restrict__ bias,
                 const int* __restrict__ perm, const int* __restrict__ cnt,
                 const int* __restrict__ off,
                 ushort* __restrict__ Cout, int N, int ldC) {
  // bijective XCD swizzle (works for any nwg)
  const int nwg = gridDim.x;
  const int qq = nwg >> 3, rr = nwg & 7;
  const int xcd = blockIdx.x & 7, idx = blockIdx.x >> 3;
  const int wgid = (xcd < rr ? xcd * (qq + 1) : rr * (qq + 1) + (xcd - rr) * qq) + idx;

  int mcnt = N, mtile, ntile;
  const int* permt = nullptr;
  const ushort* Bt = B;
  const float* biast = bias;
  if (ADAPT) {
    const int mt = nwg / (NTYPES * NTN);
    const int t = wgid / (mt * NTN);
    const int rem = wgid % (mt * NTN);
    mtile = rem / NTN;
    ntile = rem % NTN;
    mcnt = cnt[t];
    permt = perm + off[t];
    Bt = B + (size_t)t * D * KDIM;
    biast = bias + t * D;
  } else {
    mtile = wgid / NTN;
    ntile = wgid % NTN;
  }
  const int m0 = mtile * BM;
  if (m0 >= mcnt) return;
  const int n0 = ntile * BN;

  __shared__ ushort SM[2][2][BM * 32];   // [buf][A=0/B=1][row*32+k]
  static_assert(BM * BN <= 2 * 2 * BM * 32, "C tile must fit in staging LDS");

  const int tid  = threadIdx.x;
  const int lane = tid & 63;
  const int w    = tid >> 6;
  constexpr int FR = BM / 32;            // 16x16 frags per wave (rows)
  constexpr int FC = BN / 32;
  const int wr   = (w >> 1) * (BM / 2);
  const int wc   = (w & 1) * (BN / 2);

  // staging: (BM/16) x 1KB calls per matrix; wave w does calls {w, w+4, ...}.
  // XOR swizzle: content slot' = slot ^ ((row>>1)&3), applied to GLOBAL source
  // (LDS dest stays linear — global_load_lds requirement), undone at ds_read.
  constexpr int PW = BM / 16 / 4;        // calls per wave per matrix (1 or 2)
  const ushort* gA[PW];
  const ushort* gB[PW];
  int lo[PW];
#pragma unroll
  for (int u = 0; u < PW; ++u) {
    const int c  = w + u * 4;
    const int r  = c * 16 + (lane >> 2);
    const int sl = (lane & 3) ^ ((r >> 1) & 3);
    int ga;
    if (ADAPT) ga = permt[min(m0 + r, mcnt - 1)];
    else       ga = min(m0 + r, N - 1);
    gA[u] = A + (size_t)ga * KDIM + sl * 8;
    gB[u] = Bt + (size_t)(n0 + r) * KDIM + sl * 8;
    lo[u] = c * 512;                     // shorts
  }

  auto STAGE = [&](int k0, int buf) {
#pragma unroll
    for (int u = 0; u < PW; ++u) {
      GLOAD_LDS16(gA[u] + k0, &SM[buf][0][lo[u]]);
      GLOAD_LDS16(gB[u] + k0, &SM[buf][1][lo[u]]);
    }
  };

  f32x4 acc[FR][FC] = {};

  const int r15 = lane & 15;
  const int g   = lane >> 4;
  const int gsw = g ^ ((r15 >> 1) & 3);  // swizzled k-slot for frag reads

  // prologue — __syncthreads drains vmcnt (global_load_lds) + fences
  STAGE(0, 0);
  __syncthreads();

  constexpr int NT = KDIM / 32;
  int curb = 0;
#pragma unroll
  for (int kt = 0; kt < NT; ++kt) {
    if (kt + 1 < NT) STAGE((kt + 1) * 32, curb ^ 1);   // prefetch next tile

    short8 af[FR], bf[FC];
#pragma unroll
    for (int i = 0; i < FR; ++i)
      af[i] = *(const short8*)(&SM[curb][0][(wr + i * 16 + r15) * 32 + gsw * 8]);
#pragma unroll
    for (int j = 0; j < FC; ++j)
      bf[j] = *(const short8*)(&SM[curb][1][(wc + j * 16 + r15) * 32 + gsw * 8]);
#pragma unroll
    for (int i = 0; i < FR; ++i)
#pragma unroll
      for (int j = 0; j < FC; ++j)
        acc[i][j] = __builtin_amdgcn_mfma_f32_16x16x32_bf16(af[i], bf[j], acc[i][j], 0, 0, 0);

    // real barrier: drains this wave's vmcnt (prefetch landed) + lgkmcnt, and
    // is an IR fence so next iteration's STAGE cannot hoist above it.
    __syncthreads();
    curb ^= 1;
  }

  // ---- epilogue: C/D layout (m89): col = lane&15, row = (lane>>4)*4 + reg ----
  ushort* Ct = (ushort*)SM;
#pragma unroll
  for (int i = 0; i < FR; ++i) {
#pragma unroll
    for (int q4 = 0; q4 < 4; ++q4) {
      const int row = wr + i * 16 + (lane >> 4) * 4 + q4;
#pragma unroll
      for (int j = 0; j < FC; ++j) {
        const int col = wc + j * 16 + r15;
        float v = acc[i][j][q4];
        if (ADAPT) v = tanhf(v + biast[n0 + col]);
        Ct[row * BN + col] = f2b(v);
      }
    }
  }
  __syncthreads();
  // coalesced copy-out, 16B per thread per unit
  constexpr int C8 = BN / 8;
  constexpr int UNITS = BM * C8;
#pragma unroll
  for (int u0 = 0; u0 < UNITS; u0 += 256) {
    const int u = u0 + tid;
    const int row = u / C8, c8 = u % C8;
    const int rl = m0 + row;
    if (rl < mcnt) {
      const int grow = ADAPT ? permt[rl] : rl;
      *(short8*)(Cout + (size_t)grow * ldC + n0 + c8 * 8) =
          *(const short8*)(Ct + row * BN + c8 * 8);
    }
  }
}

// ---------------- CSR gather-combine ----------------
// out[v] = relu( (sum_{e in in(v)} Hall[src_e][rel_e*256 + :]) * inv[v]
//                + Hall[v][6*256 + :] + bias )
// one wave per node, lane owns 4 channels; edge loop 8-wide unrolled so 8
// independent L2/L3 gathers are in flight per wave.
template <bool LAST>
__global__ void k_combine(const ushort* __restrict__ Hall, const int* __restrict__ rowptr,
                          const int* __restrict__ epack, const float* __restrict__ invd,
                          const float* __restrict__ bias, void* __restrict__ outp, int N) {
  int v = blockIdx.x * 4 + (threadIdx.x >> 6);
  if (v >= N) return;
  int lane = threadIdx.x & 63;
  int e0 = rowptr[v], e1 = rowptr[v + 1];
  // hoisted tail operands (overlap with gather loop)
  const uint2 s = *(const uint2*)(Hall + (size_t)v * LDH + NREL * D + lane * 4);
  float iv = invd[v];
  const float4 b4 = *(const float4*)(bias + lane * 4);

  float a0 = 0.f, a1 = 0.f, a2 = 0.f, a3 = 0.f;
  int e = e0;
  for (; e + 8 <= e1; e += 8) {
    uint2 u[8];
#pragma unroll
    for (int k = 0; k < 8; ++k) {
      int p = epack[e + k];
      u[k] = *(const uint2*)(Hall + (size_t)(p >> 3) * LDH + (p & 7) * D + lane * 4);
    }
#pragma unroll
    for (int k = 0; k < 8; ++k) {
      a0 += b2f(u[k].x & 0xffffu);
      a1 += __uint_as_float(u[k].x & 0xffff0000u);
      a2 += b2f(u[k].y & 0xffffu);
      a3 += __uint_as_float(u[k].y & 0xffff0000u);
    }
  }
  if (e + 4 <= e1) {
    uint2 u[4];
#pragma unroll
    for (int k = 0; k < 4; ++k) {
      int p = epack[e + k];
      u[k] = *(const uint2*)(Hall + (size_t)(p >> 3) * LDH + (p & 7) * D + lane * 4);
    }
#pragma unroll
    for (int k = 0; k < 4; ++k) {
      a0 += b2f(u[k].x & 0xffffu);
      a1 += __uint_as_float(u[k].x & 0xffff0000u);
      a2 += b2f(u[k].y & 0xffffu);
      a3 += __uint_as_float(u[k].y & 0xffff0000u);
    }
    e += 4;
  }
  for (; e < e1; ++e) {
    int p = epack[e];
    const uint2 u = *(const uint2*)(Hall + (size_t)(p >> 3) * LDH + (p & 7) * D + lane * 4);
    a0 += b2f(u.x & 0xffffu);
    a1 += __uint_as_float(u.x & 0xffff0000u);
    a2 += b2f(u.y & 0xffffu);
    a3 += __uint_as_float(u.y & 0xffff0000u);
  }
  float o0 = fmaxf(fmaf(a0, iv, b2f(s.x & 0xffffu)) + b4.x, 0.f);
  float o1 = fmaxf(fmaf(a1, iv, __uint_as_float(s.x & 0xffff0000u)) + b4.y, 0.f);
  float o2 = fmaxf(fmaf(a2, iv, b2f(s.y & 0xffffu)) + b4.z, 0.f);
  float o3 = fmaxf(fmaf(a3, iv, __uint_as_float(s.y & 0xffff0000u)) + b4.w, 0.f);
  if (LAST) {
    float4 o; o.x = o0; o.y = o1; o.z = o2; o.w = o3;
    ((float4*)outp)[(size_t)v * 64 + lane] = o;
  } else {
    ushort4 o; o.x = f2b(o0); o.y = f2b(o1); o.z = f2b(o2); o.w = f2b(o3);
    ((ushort4*)outp)[(size_t)v * 64 + lane] = o;
  }
}

extern "C" void kernel_launch(void* const* d_in, const int* in_sizes, int n_in,
                              void* d_out, int out_size, void* d_ws, size_t ws_size,
                              hipStream_t stream) {
  const float* X       = (const float*)d_in[0];
  const int*   ntype   = (const int*)d_in[1];
  const int*   eidx    = (const int*)d_in[2];
  const int*   etype   = (const int*)d_in[3];
  const float* adapt_W = (const float*)d_in[5];
  const float* adapt_b = (const float*)d_in[6];
  const float* W_rel   = (const float*)d_in[7];
  const float* W_self  = (const float*)d_in[8];
  const float* b_self  = (const float*)d_in[9];

  const int N = in_sizes[1];
  const int E = in_sizes[3];
  const int* src = eidx;
  const int* dst = eidx + E;

  char* ws = (char*)d_ws;
  size_t o = 0;
  auto alloc = [&](size_t bytes) { void* p = ws + o; o += (bytes + 255) & ~255ull; return p; };

  ushort* Hall  = (ushort*)alloc((size_t)N * LDH * 2);  // 71.7 MB; also aliases Xb
  ushort* Xb    = Hall;                                  // Xb (20.5 MB) dead before Hall written
  ushort* h     = (ushort*)alloc((size_t)N * D * 2);
  ushort* Wab   = (ushort*)alloc((size_t)NTYPES * D * DIN * 2);
  ushort* Wcat  = (ushort*)alloc((size_t)2 * NSLOT * D * D * 2);
  int*   deg    = (int*)alloc((size_t)N * 4);
  float* inv    = (float*)alloc((size_t)N * 4);
  int*   perm   = (int*)alloc((size_t)N * 4);
  int*   rowptr = (int*)alloc((size_t)(N + 1) * 4);
  int*   cursor = (int*)alloc((size_t)N * 4);
  int*   epack  = (int*)alloc((size_t)E * 4);
  int*   bsum   = (int*)alloc(1024 * 4);
  int*   blockcnt = (int*)alloc((size_t)1024 * NTYPES * 4);
  int*   boffset  = (int*)alloc((size_t)1024 * NTYPES * 4);
  int*   cnt    = (int*)alloc(NTYPES * 4);
  int*   offt   = (int*)alloc(NTYPES * 4);

  hipMemsetAsync(deg, 0, (size_t)N * 4, stream);

  const int thr = 256;
  const int nbN = (N + thr - 1) / thr;
  const int nbE = (E + thr - 1) / thr;

  // bf16 conversions / weight packing
  k_cvt_bf16<<<(N * DIN / 4 + thr - 1) / thr, thr, 0, stream>>>(X, Xb, N * DIN / 4);
  k_cvt_bf16<<<(NTYPES * D * DIN / 4 + thr - 1) / thr, thr, 0, stream>>>(adapt_W, Wab,
                                                                          NTYPES * D * DIN / 4);
  dim3 gW(D * D / 256, NSLOT, 2);
  k_pack_wcat<<<gW, 256, 0, stream>>>(W_rel, W_self, Wcat);

  // type sort (ballot-based, contention-free) + degrees
  k_type_blockcnt<<<nbN, thr, 0, stream>>>(ntype, blockcnt, N);
  k_type_scan<<<1, 64, 0, stream>>>(blockcnt, boffset, cnt, offt, nbN);
  k_type_scatter<<<nbN, thr, 0, stream>>>(ntype, boffset, perm, N);
  k_degree<<<nbE, thr, 0, stream>>>(dst, deg, E);
  k_invdeg<<<nbN, thr, 0, stream>>>(deg, inv, N);

  // CSR by dst
  k_scan_block<<<nbN, 256, 0, stream>>>(deg, rowptr, bsum, N);
  k_scan_bsum<<<1, 64, 0, stream>>>(bsum, nbN);
  k_scan_add<<<nbN, 256, 0, stream>>>(rowptr, cursor, bsum, N, E);
  k_sortedges<<<nbE, 256, 0, stream>>>(src, dst, etype, cursor, epack, E);

  // adaptation: h = tanh(X @ W_t^T + b_t), bf16 out — 64x64 tiles, 1D swizzled grid
  const int mtA = (N + 63) / 64;
  const int nwgA = NTYPES * mtA * (D / 64);
  k_mfma_gemm<64, 64, D / 64, DIN, true, 6><<<nwgA, 256, 0, stream>>>(
      Xb, Wab, adapt_b, perm, cnt, offt, h, N, D);

  // two relational layers — 128x128 tiles, n-fast 1D grid + XCD swizzle
  const int mtL = (N + 127) / 128;
  const int nwgL = mtL * (LDH / 128);
  for (int l = 0; l < 2; ++l) {
    const ushort* Wl = Wcat + (size_t)l * NSLOT * D * D;
    k_mfma_gemm<128, 128, LDH / 128, D, false, 4><<<nwgL, 256, 0, stream>>>(
        h, Wl, nullptr, nullptr, nullptr, nullptr, Hall, N, LDH);
    if (l == 0)
      k_combine<false><<<(N + 3) / 4, 256, 0, stream>>>(Hall, rowptr, epack, inv,
                                                        b_self + (size_t)l * D, h, N);
    else
      k_combine<true><<<(N + 3) / 4, 256, 0, stream>>>(Hall, rowptr, epack, inv,
                                                       b_self + (size_t)l * D, d_out, N);
  }
}